// Round 14
// baseline (908.690 us; speedup 1.0000x reference)
//
#include <hip/hip_runtime.h>
#include <hip/hip_bf16.h>

// ---------------------------------------------------------------------------
// graphNN round 14 (= R13 + persistent k_edge, spill-fixed):
//  - k_edge: persistent 512 blocks; W staged once/block (16KB); next-tile
//    Z/eid register-prefetch hidden under C-write+walk. R11's spill fixed:
//    launch_bounds(1024,4) -> 128 VGPR cap (R11 had (1024,8) -> 64 -> spill).
//    LDS 48.5KB: W[0,16K) persistent | X[16K,32K) | C overlay [16K,48K) | sN.
//  - numerics byte-identical to R13 (absmax 2.93e-3 margin preserved)
// ---------------------------------------------------------------------------

typedef __attribute__((ext_vector_type(8))) short short8;
typedef __attribute__((ext_vector_type(4))) float f32x4;
typedef __attribute__((ext_vector_type(4))) unsigned u32x4;
typedef unsigned short ushort_t;
typedef unsigned char uchar_t;

static __device__ __forceinline__ unsigned short f2bf(float x) {
  union { float f; unsigned u; } v{x};
  unsigned r = v.u + 0x7FFF + ((v.u >> 16) & 1);
  return (unsigned short)(r >> 16);
}
static __device__ __forceinline__ float bf2f(unsigned short h) {
  union { unsigned u; float f; } v{(unsigned)h << 16};
  return v.f;
}
static __device__ __forceinline__ float u2f(unsigned u) {
  union { unsigned u; float f; } v{u};
  return v.f;
}
static __device__ __forceinline__ unsigned cvtpk(float a, float b) {
  unsigned r;
  asm("v_cvt_pk_bf16_f32 %0, %1, %2" : "=v"(r) : "v"(a), "v"(b));
  return r;
}
static __device__ __forceinline__ uchar_t f2fp8(float x) {
  return (uchar_t)(__builtin_amdgcn_cvt_pk_fp8_f32(x, 0.f, 0, false) & 0xff);
}
static __device__ __forceinline__ ushort_t pk2fp8(float a, float b) {
  return (ushort_t)(__builtin_amdgcn_cvt_pk_fp8_f32(a, b, 0, false) & 0xffff);
}

// ---------- fused init: deg histogram (blocks 0..1023) + weight prep --------
__global__ void k_init(const int* __restrict__ dst, int* __restrict__ deg, int E,
                       const float* __restrict__ msg_W, const float* __restrict__ W1,
                       const float* __restrict__ W2, ushort_t* __restrict__ WfT,
                       ushort_t* __restrict__ WfB, ushort_t* __restrict__ Wf1,
                       ushort_t* __restrict__ Wf2) {
  if (blockIdx.x < 1024) {
    int i = blockIdx.x * 256 + threadIdx.x;
    int stride = 1024 * 256;
    for (; i < E; i += stride) atomicAdd(&deg[dst[i]], 1);
    return;
  }
  int id = (blockIdx.x - 1024) * 256 + threadIdx.x;
  const float* W;
  ushort_t* dh;
  int lid;
  if (id < 16384) {  // WfT: KC=2
    W = msg_W; dh = WfT; lid = id;
  } else if (id < 24576) {  // WfB: KC=1
    W = msg_W + 128 * 128; dh = WfB; lid = id - 16384;
  } else if (id < 122880) {  // Wf1: 3 slices, KC=4
    int sub = id - 24576;
    int s = sub >> 15;
    lid = sub & 32767;
    W = W1 + (size_t)s * 256 * 128;
    dh = Wf1 + (size_t)s * 32768;
  } else if (id < 172032) {  // Wf2: 3 slices, KC=2
    int sub = id - 122880;
    int s = sub >> 14;
    lid = sub & 16383;
    W = W2 + (size_t)s * 128 * 128;
    dh = Wf2 + (size_t)s * 16384;
  } else {
    return;
  }
  int j = lid & 7;
  int l = (lid >> 3) & 63;
  int rest = lid >> 9;
  int ks = rest & 1, nt = (rest >> 1) & 7, kc = rest >> 4;
  int k = kc * 64 + ks * 32 + (l >> 4) * 8 + j;
  int col = nt * 16 + (l & 15);
  dh[lid] = f2bf(W[(size_t)k * 128 + col]);
}

// ---------- CSR fill ----------
__global__ void k_csr(const int* __restrict__ src, const int* __restrict__ dst,
                      int* __restrict__ cursor, int* __restrict__ csr_srcnode,
                      int* __restrict__ csr_eid, int* __restrict__ pos2node, int E) {
  int i = blockIdx.x * blockDim.x + threadIdx.x;
  int stride = gridDim.x * blockDim.x;
  for (; i < E; i += stride) {
    int d = dst[i];
    int pos = atomicAdd(&cursor[d], 1);
    csr_srcnode[pos] = src[i];
    csr_eid[pos] = i;
    pos2node[pos] = d;
  }
}

// stage 16 fp32 -> bf16-hi LDS fragment slots
static __device__ __forceinline__ void stage_hi(const float* base, int sq, int sr,
                                                ushort_t* Xh) {
#pragma unroll
  for (int i2 = 0; i2 < 2; ++i2) {
    const int o = sq * 2 + i2;
    f32x4 a4 = *(const f32x4*)(base + sq * 16 + i2 * 8);
    f32x4 b4 = *(const f32x4*)(base + sq * 16 + i2 * 8 + 4);
    u32x4 vh;
    vh[0] = cvtpk(a4[0], a4[1]);
    vh[1] = cvtpk(a4[2], a4[3]);
    vh[2] = cvtpk(b4[0], b4[1]);
    vh[3] = cvtpk(b4[2], b4[3]);
    const int slot = (sr >> 4) * 128 + o * 16 + (sr & 15);
    *(u32x4*)(Xh + (size_t)slot * 8) = vh;
  }
}

// ---------- fused: block 0 = scan(deg->offs,cursor,norm); rest = Z GEMM -----
__global__ __launch_bounds__(256) void k_scan_mmz(
    const int* __restrict__ deg, float* __restrict__ norm, int* __restrict__ offs,
    int* __restrict__ cursor, int N, const float* __restrict__ A0,
    const ushort_t* __restrict__ Wf, const float* __restrict__ bias,
    uchar_t* __restrict__ outZ8, int KC) {
  __shared__ __align__(16) char lds[24576];
  if (blockIdx.x == 0) {
    int* part = (int*)lds;
    const int t = threadIdx.x;
    const int C = (N + 255) >> 8;
    const int b = t * C, e = min(b + C, N);
    int s = 0;
    for (int i = b; i < e; ++i) s += deg[i];
    part[t] = s;
    __syncthreads();
    for (int ofs = 1; ofs < 256; ofs <<= 1) {
      int v = (t >= ofs) ? part[t - ofs] : 0;
      __syncthreads();
      part[t] += v;
      __syncthreads();
    }
    int base = (t == 0) ? 0 : part[t - 1];
    for (int i = b; i < e; ++i) {
      offs[i] = base;
      cursor[i] = base;
      int d = deg[i];
      base += d;
      norm[i] = rsqrtf((float)max(d, 1));
    }
    if (t == 0) offs[N] = part[255];
    return;
  }
  ushort_t* Xh = (ushort_t*)lds;            // 8KB
  ushort_t* Whi = (ushort_t*)(lds + 8192);  // 16KB
  const int t = threadIdx.x;
  const int m0 = (blockIdx.x - 1) * 64;
  const int l = t & 63, mt = t >> 6;
  const int sr = t & 63, sq = t >> 6;
  const int row = min(m0 + sr, N - 1);

  f32x4 acc[8];
#pragma unroll
  for (int nt = 0; nt < 8; ++nt) acc[nt] = (f32x4){0.f, 0.f, 0.f, 0.f};

  for (int kc = 0; kc < KC; ++kc) {
    __syncthreads();
    {
      const ulong2* gh = (const ulong2*)(Wf + (size_t)kc * 8192);
#pragma unroll
      for (int i = 0; i < 4; ++i) ((ulong2*)Whi)[i * 256 + t] = gh[i * 256 + t];
    }
    stage_hi(A0 + (size_t)row * 128 + kc * 64, sq, sr, Xh);
    __syncthreads();
    const short8* Xh8 = (const short8*)Xh;
    const short8* Wh8 = (const short8*)Whi;
#pragma unroll
    for (int ks = 0; ks < 2; ++ks) {
      short8 ah = Xh8[mt * 128 + ks * 64 + l];
#pragma unroll
      for (int nt = 0; nt < 8; ++nt)
        acc[nt] = __builtin_amdgcn_mfma_f32_16x16x32_bf16(
            ah, Wh8[(nt * 2 + ks) * 64 + l], acc[nt], 0, 0, 0);
    }
  }
  const int l15 = l & 15, lh = l >> 4;
#pragma unroll
  for (int nt = 0; nt < 8; ++nt) {
    const int col = nt * 16 + l15;
#pragma unroll
    for (int rg = 0; rg < 4; ++rg) {
      const int r = m0 + mt * 16 + lh * 4 + rg;
      if (r < N) outZ8[(size_t)r * 128 + col] = f2fp8(acc[nt][rg] + bias[col]);
    }
  }
}

// ---------- fused 3-slice GEMM: YA bf16, YBt bf16, YC8 fp8 ------------------
template <int BF16A>
__global__ __launch_bounds__(256) void k_mm3(
    const void* __restrict__ A0v, const float* __restrict__ A1, int split64,
    const ushort_t* __restrict__ Wf, const float* __restrict__ rowscale,
    ushort_t* __restrict__ outYA, ushort_t* __restrict__ outYB,
    uchar_t* __restrict__ outYC8, int M, int KC) {
  __shared__ __align__(16) char lds[24576];
  ushort_t* Xh = (ushort_t*)lds;            // 8KB
  ushort_t* Whi = (ushort_t*)(lds + 8192);  // 16KB

  const int t = threadIdx.x;
  const int m0 = blockIdx.x * 64;
  const int l = t & 63, mt = t >> 6;
  const int sr = t & 63, sq = t >> 6;
  const int row = min(m0 + sr, M - 1);

  f32x4 acc[3][8];
#pragma unroll
  for (int s = 0; s < 3; ++s)
#pragma unroll
    for (int nt = 0; nt < 8; ++nt) acc[s][nt] = (f32x4){0.f, 0.f, 0.f, 0.f};

  for (int kc = 0; kc < KC; ++kc) {
    __syncthreads();
    if constexpr (BF16A) {
      const ushort_t* base = (const ushort_t*)A0v + (size_t)row * 128 + kc * 64;
#pragma unroll
      for (int i2 = 0; i2 < 2; ++i2) {
        const int o = sq * 2 + i2;
        short8 v = *(const short8*)(base + sq * 16 + i2 * 8);
        const int slot = (sr >> 4) * 128 + o * 16 + (sr & 15);
        *(short8*)(Xh + (size_t)slot * 8) = v;
      }
    } else {
      const float* A0 = (const float*)A0v;
      const float* base = (kc < split64) ? (A0 + (size_t)row * 128 + kc * 64)
                                         : (A1 + (size_t)row * 128 + (kc - split64) * 64);
      stage_hi(base, sq, sr, Xh);
    }
#pragma unroll
    for (int s = 0; s < 3; ++s) {
      if (s) __syncthreads();
      {
        const ulong2* gh = (const ulong2*)(Wf + ((size_t)s * KC + kc) * 8192);
#pragma unroll
        for (int i = 0; i < 4; ++i) ((ulong2*)Whi)[i * 256 + t] = gh[i * 256 + t];
      }
      __syncthreads();
      const short8* Xh8 = (const short8*)Xh;
      const short8* Wh8 = (const short8*)Whi;
#pragma unroll
      for (int ks = 0; ks < 2; ++ks) {
        short8 ah = Xh8[mt * 128 + ks * 64 + l];
#pragma unroll
        for (int nt = 0; nt < 8; ++nt)
          acc[s][nt] = __builtin_amdgcn_mfma_f32_16x16x32_bf16(
              ah, Wh8[(nt * 2 + ks) * 64 + l], acc[s][nt], 0, 0, 0);
      }
    }
  }
  const int l15 = l & 15, lh = l >> 4;
#pragma unroll
  for (int rg = 0; rg < 4; ++rg) {
    const int r = m0 + mt * 16 + lh * 4 + rg;
    if (r < M) {
      const float rs = rowscale[r];
#pragma unroll
      for (int nt = 0; nt < 8; ++nt) {
        const int col = nt * 16 + l15;
        outYA[(size_t)r * 128 + col] = f2bf(acc[0][nt][rg]);
        outYB[(size_t)r * 128 + col] = f2bf(acc[1][nt][rg] * rs);
        outYC8[(size_t)r * 128 + col] = f2fp8(acc[2][nt][rg] * rs);
      }
    }
  }
}

// ---------- persistent edge GEMM: W once/block, cross-tile Z prefetch -------
// LDS: W[0,16K) persistent | X[16K,32K) | C overlay [16K,48K) | sN [48K,+512)
__global__ __launch_bounds__(1024, 4) void k_edge(
    const float* __restrict__ ef, const int* __restrict__ csr_srcnode,
    const int* __restrict__ csr_eid, const int* __restrict__ pos2node,
    const ushort_t* __restrict__ WfB, const uchar_t* __restrict__ Z8,
    float* __restrict__ h_neigh, int nT) {
  __shared__ __align__(16) char lds[49664];
  ushort_t* Whi = (ushort_t*)lds;            // [0,16K) persistent
  ushort_t* Xh = (ushort_t*)(lds + 16384);   // [16K,32K)
  ushort_t* Cs = (ushort_t*)(lds + 16384);   // overlay [16K,48K): 128x128 bf16
  int* sN = (int*)(lds + 49152);             // [48K,48K+512)

  const int t = threadIdx.x;
  const int l = t & 63, w = t >> 6;          // 16 waves
  const int mt = w >> 1, nh = w & 1;         // M-tile 0..7, N-half
  const int col = t & 127, g = t >> 7;       // 8 walk groups x 16 rows
  const int erow = t >> 3, epart = t & 7;    // ef staging coords
  const int l15 = l & 15, lh = l >> 4;

  // ---- stage W once per block ----
  ((ulong2*)Whi)[t] = ((const ulong2*)WfB)[t];

  // ---- prologue: prefetch tile0's Z + eid ----
  int tile = blockIdx.x;
  uchar_t z8[16];
  int eid = 0;
  if (tile < nT) {
    const int b0 = tile * 128;
#pragma unroll
    for (int i = 0; i < 16; ++i)
      z8[i] = Z8[(size_t)csr_srcnode[b0 + g * 16 + i] * 128 + col];
    eid = csr_eid[b0 + erow];
  }

  for (; tile < nT; tile += gridDim.x) {
    const int b0 = tile * 128;
    // ---- (A) stage ef rows (current) + sN ----
    {
      const float* rowp = ef + (size_t)eid * 64 + epart * 8;
      f32x4 a4 = __builtin_nontemporal_load((const f32x4*)rowp);
      f32x4 b4 = __builtin_nontemporal_load((const f32x4*)(rowp + 4));
      u32x4 vh;
      vh[0] = cvtpk(a4[0], a4[1]);
      vh[1] = cvtpk(a4[2], a4[3]);
      vh[2] = cvtpk(b4[0], b4[1]);
      vh[3] = cvtpk(b4[2], b4[3]);
      const int slot = (erow >> 4) * 128 + epart * 16 + (erow & 15);
      *(u32x4*)(Xh + (size_t)slot * 8) = vh;
      if (t < 128) sN[t] = pos2node[b0 + t];
    }
    // ---- issue next-tile Z + eid prefetch (lands during C-write + walk) ----
    uchar_t z8n[16];
    int eidn = 0;
    {
      const int ntile = tile + gridDim.x;
      if (ntile < nT) {
        const int nb0 = ntile * 128;
#pragma unroll
        for (int i = 0; i < 16; ++i)
          z8n[i] = Z8[(size_t)csr_srcnode[nb0 + g * 16 + i] * 128 + col];
        eidn = csr_eid[nb0 + erow];
      }
    }
    __syncthreads();  // X, sN, (W on first iter) visible
    // ---- (B) MFMA ----
    f32x4 acc[4];
#pragma unroll
    for (int nt = 0; nt < 4; ++nt) acc[nt] = (f32x4){0.f, 0.f, 0.f, 0.f};
    {
      const short8* Xh8 = (const short8*)Xh;
      const short8* Wh8 = (const short8*)Whi;
#pragma unroll
      for (int ks = 0; ks < 2; ++ks) {
        short8 ah = Xh8[mt * 128 + ks * 64 + l];
#pragma unroll
        for (int nt = 0; nt < 4; ++nt) {
          const int ntg = nh * 4 + nt;
          acc[nt] = __builtin_amdgcn_mfma_f32_16x16x32_bf16(
              ah, Wh8[(ntg * 2 + ks) * 64 + l], acc[nt], 0, 0, 0);
        }
      }
    }
    __syncthreads();  // MFMA done -> C region (over X) writable
    // ---- (C) write C tile (bank-correct swizzle) ----
#pragma unroll
    for (int nt = 0; nt < 4; ++nt) {
#pragma unroll
      for (int rg = 0; rg < 4; ++rg) {
        const int row = mt * 16 + lh * 4 + rg;
        const int c = nh * 64 + nt * 16 + l15;
        Cs[row * 128 + (c ^ (((row >> 2) & 3) << 4))] = f2bf(acc[nt][rg]);
      }
    }
    __syncthreads();  // C visible
    // ---- (D) 8-way parallel segment walk ----
    {
      int node = sN[g * 16];
      float ssum = 0.f;
#pragma unroll
      for (int r = 0; r < 16; ++r) {
        const int rr = g * 16 + r;
        float cz = bf2f(Cs[rr * 128 + (col ^ (((rr >> 2) & 3) << 4))]);
        float zf = __builtin_amdgcn_cvt_f32_fp8((int)z8[r], 0);
        float v = fmaxf(cz + zf, 0.f);
        if (r == 0) {
          ssum = v;
        } else {
          int n2 = sN[rr];
          if (n2 == node) {
            ssum += v;
          } else {
            unsafeAtomicAdd(&h_neigh[(size_t)node * 128 + col], ssum);
            node = n2;
            ssum = v;
          }
        }
      }
      unsafeAtomicAdd(&h_neigh[(size_t)node * 128 + col], ssum);
    }
    // rotate prefetched state
#pragma unroll
    for (int i = 0; i < 16; ++i) z8[i] = z8n[i];
    eid = eidn;
    __syncthreads();  // walk done -> next iter may overwrite X/C/sN
  }
}

// ---------- propA: Qt8 = fp8(YBt + n^2 * sum YC8[src])  (4-acc ILP) ---------
__global__ __launch_bounds__(256) void k_propA(
    const uchar_t* __restrict__ YC8, const ushort_t* __restrict__ YBt,
    const int* __restrict__ offs, const int* __restrict__ csr_src,
    const float* __restrict__ norm, uchar_t* __restrict__ Qt8, int N) {
  const int v = blockIdx.x * 4 + (threadIdx.x >> 6);
  const int lane = threadIdx.x & 63;
  if (v >= N) return;
  const int b = offs[v], e = offs[v + 1];
  const ushort_t* yc = (const ushort_t*)YC8;
  float ax0 = 0.f, ay0 = 0.f, ax1 = 0.f, ay1 = 0.f;
  float ax2 = 0.f, ay2 = 0.f, ax3 = 0.f, ay3 = 0.f;
  int i = b;
  const int e4 = b + ((e - b) & ~3);
  for (; i < e4; i += 4) {
    const int s0 = csr_src[i], s1 = csr_src[i + 1];
    const int s2 = csr_src[i + 2], s3 = csr_src[i + 3];
    const int x0 = yc[(size_t)s0 * 64 + lane];
    const int x1 = yc[(size_t)s1 * 64 + lane];
    const int x2 = yc[(size_t)s2 * 64 + lane];
    const int x3 = yc[(size_t)s3 * 64 + lane];
    auto d0 = __builtin_amdgcn_cvt_pk_f32_fp8(x0, false);
    auto d1 = __builtin_amdgcn_cvt_pk_f32_fp8(x1, false);
    auto d2 = __builtin_amdgcn_cvt_pk_f32_fp8(x2, false);
    auto d3 = __builtin_amdgcn_cvt_pk_f32_fp8(x3, false);
    ax0 += d0[0]; ay0 += d0[1];
    ax1 += d1[0]; ay1 += d1[1];
    ax2 += d2[0]; ay2 += d2[1];
    ax3 += d3[0]; ay3 += d3[1];
  }
  for (; i < e; ++i) {
    const int x = yc[(size_t)csr_src[i] * 64 + lane];
    auto d = __builtin_amdgcn_cvt_pk_f32_fp8(x, false);
    ax0 += d[0]; ay0 += d[1];
  }
  const float ax = (ax0 + ax1) + (ax2 + ax3);
  const float ay = (ay0 + ay1) + (ay2 + ay3);
  const float n = norm[v];
  const float n2 = n * n;
  const unsigned yb = ((const unsigned*)YBt)[(size_t)v * 64 + lane];
  ((ushort_t*)Qt8)[(size_t)v * 64 + lane] =
      pk2fp8(u2f(yb << 16) + n2 * ax, u2f(yb & 0xffff0000u) + n2 * ay);
}

// ---------- propB: H = bf16(relu(YA + n * sum Qt8[src] + b)) ----------------
__global__ __launch_bounds__(256) void k_propB(
    const uchar_t* __restrict__ Qt8, const ushort_t* __restrict__ YAb,
    const float* __restrict__ bias, const int* __restrict__ offs,
    const int* __restrict__ csr_src, const float* __restrict__ norm,
    ushort_t* __restrict__ H, int N) {
  const int v = blockIdx.x * 4 + (threadIdx.x >> 6);
  const int lane = threadIdx.x & 63;
  if (v >= N) return;
  const int b = offs[v], e = offs[v + 1];
  const ushort_t* qp = (const ushort_t*)Qt8;
  float ax0 = 0.f, ay0 = 0.f, ax1 = 0.f, ay1 = 0.f;
  float ax2 = 0.f, ay2 = 0.f, ax3 = 0.f, ay3 = 0.f;
  int i = b;
  const int e4 = b + ((e - b) & ~3);
  for (; i < e4; i += 4) {
    const int s0 = csr_src[i], s1 = csr_src[i + 1];
    const int s2 = csr_src[i + 2], s3 = csr_src[i + 3];
    const int x0 = qp[(size_t)s0 * 64 + lane];
    const int x1 = qp[(size_t)s1 * 64 + lane];
    const int x2 = qp[(size_t)s2 * 64 + lane];
    const int x3 = qp[(size_t)s3 * 64 + lane];
    auto d0 = __builtin_amdgcn_cvt_pk_f32_fp8(x0, false);
    auto d1 = __builtin_amdgcn_cvt_pk_f32_fp8(x1, false);
    auto d2 = __builtin_amdgcn_cvt_pk_f32_fp8(x2, false);
    auto d3 = __builtin_amdgcn_cvt_pk_f32_fp8(x3, false);
    ax0 += d0[0]; ay0 += d0[1];
    ax1 += d1[0]; ay1 += d1[1];
    ax2 += d2[0]; ay2 += d2[1];
    ax3 += d3[0]; ay3 += d3[1];
  }
  for (; i < e; ++i) {
    const int x = qp[(size_t)csr_src[i] * 64 + lane];
    auto d = __builtin_amdgcn_cvt_pk_f32_fp8(x, false);
    ax0 += d[0]; ay0 += d[1];
  }
  const float ax = (ax0 + ax1) + (ax2 + ax3);
  const float ay = (ay0 + ay1) + (ay2 + ay3);
  const float n = norm[v];
  const unsigned ya = ((const unsigned*)YAb)[(size_t)v * 64 + lane];
  const float2 bb = ((const float2*)bias)[lane];
  const float hx = fmaxf(u2f(ya << 16) + n * ax + bb.x, 0.f);
  const float hy = fmaxf(u2f(ya & 0xffff0000u) + n * ay + bb.y, 0.f);
  ((unsigned*)H)[(size_t)v * 64 + lane] = cvtpk(hx, hy);
}

// ---------- column sums of bf16 h -> hg[128] ----------
__global__ void k_colsum(const ushort_t* __restrict__ h, float* __restrict__ hg, int N) {
  const int t = threadIdx.x;  // 128
  const int per = (N + gridDim.x - 1) / gridDim.x;
  const int n0 = blockIdx.x * per, n1 = min(n0 + per, N);
  float s = 0.f;
  for (int n = n0; n < n1; ++n) s += bf2f(h[(size_t)n * 128 + t]);
  unsafeAtomicAdd(&hg[t], s);
}

// ---------- final ----------
__global__ void k_final(const float* __restrict__ hg, const float* __restrict__ Wp,
                        const float* __restrict__ bp, float* __restrict__ out,
                        float invN) {
  __shared__ float red[128];
  const int t = threadIdx.x;
  red[t] = hg[t] * invN * Wp[t];
  __syncthreads();
  for (int s = 64; s > 0; s >>= 1) {
    if (t < s) red[t] += red[t + s];
    __syncthreads();
  }
  if (t == 0) out[0] = red[0] + bp[0];
}

extern "C" void kernel_launch(void* const* d_in, const int* in_sizes, int n_in,
                              void* d_out, int out_size, void* d_ws, size_t ws_size,
                              hipStream_t stream) {
  const float* node_fea = (const float*)d_in[0];
  const float* edge_fea = (const float*)d_in[1];
  const int* src = (const int*)d_in[2];
  const int* dst = (const int*)d_in[3];
  const float* msg_W = (const float*)d_in[4];
  const float* msg_b = (const float*)d_in[5];
  const float* W1 = (const float*)d_in[6];
  const float* b1 = (const float*)d_in[7];
  const float* W2 = (const float*)d_in[8];
  const float* b2 = (const float*)d_in[9];
  const float* Wp = (const float*)d_in[10];
  const float* bp = (const float*)d_in[11];

  const int N = in_sizes[0] / 128;  // 50000
  const int E = in_sizes[2];        // 1600000

  char* p = (char*)d_ws;
  auto alloc = [&](size_t bytes) {
    char* r = p;
    p += (bytes + 255) & ~(size_t)255;
    return r;
  };
  int* deg = (int*)alloc((size_t)N * 4);
  float* norm = (float*)alloc((size_t)N * 4);
  int* offs = (int*)alloc((size_t)(N + 1) * 4);
  int* cursor = (int*)alloc((size_t)N * 4);
  int* csr_srcnode = (int*)alloc((size_t)E * 4);
  int* csr_eid = (int*)alloc((size_t)E * 4);
  int* pos2node = (int*)alloc((size_t)E * 4);
  ushort_t* WfT = (ushort_t*)alloc(2 * 8192 * 2);
  ushort_t* WfB = (ushort_t*)alloc(1 * 8192 * 2);
  ushort_t* Wf1 = (ushort_t*)alloc(3 * 4 * 8192 * 2);
  ushort_t* Wf2 = (ushort_t*)alloc(3 * 2 * 8192 * 2);
  uchar_t* Z8 = (uchar_t*)alloc((size_t)N * 128);         // fp8 Z
  ushort_t* YAb = (ushort_t*)alloc((size_t)N * 128 * 2);  // bf16 YA
  float* hn = (float*)alloc((size_t)N * 128 * 4);
  ushort_t* YBt = (ushort_t*)alloc((size_t)N * 128 * 2);  // bf16 (streamed)
  uchar_t* YC8 = (uchar_t*)alloc((size_t)N * 128);        // fp8 (gathered)
  uchar_t* Qt8 = (uchar_t*)alloc((size_t)N * 128);        // fp8 (gathered)
  ushort_t* H1 = (ushort_t*)alloc((size_t)N * 128 * 2);
  ushort_t* H2 = (ushort_t*)alloc((size_t)N * 128 * 2);
  float* hg = (float*)alloc(128 * 4);

  (void)hipMemsetAsync(deg, 0, (size_t)N * 4, stream);
  (void)hipMemsetAsync(hn, 0, (size_t)N * 128 * 4, stream);
  (void)hipMemsetAsync(hg, 0, 128 * 4, stream);

  // fused: deg histogram + all weight prep
  k_init<<<1696, 256, 0, stream>>>(dst, deg, E, msg_W, W1, W2, WfT, WfB, Wf1, Wf2);

  const int MB = (N + 63) / 64;  // 782
  const int PB = (N + 3) / 4;

  // fused: scan (block 0) + Z = node_fea @ W_top + b (blocks 1..MB)
  k_scan_mmz<<<MB + 1, 256, 0, stream>>>(deg, norm, offs, cursor, N, node_fea,
                                         WfT, msg_b, Z8, 2);
  // CSR fill
  k_csr<<<2048, 256, 0, stream>>>(src, dst, cursor, csr_srcnode, csr_eid, pos2node, E);
  // edge messages -> hn (persistent, spill-safe)
  k_edge<<<512, 1024, 0, stream>>>(edge_fea, csr_srcnode, csr_eid, pos2node,
                                   WfB, Z8, hn, E / 128);

  // ----- layer 1: A = [node_fea | hn] fp32, K=256 -----
  k_mm3<0><<<MB, 256, 0, stream>>>(node_fea, hn, 2, Wf1, norm, YAb, YBt, YC8, N, 4);
  k_propA<<<PB, 256, 0, stream>>>(YC8, YBt, offs, csr_srcnode, norm, Qt8, N);
  k_propB<<<PB, 256, 0, stream>>>(Qt8, YAb, b1, offs, csr_srcnode, norm, H1, N);

  // ----- layer 2: A = H1 bf16, K=128 -----
  k_mm3<1><<<MB, 256, 0, stream>>>(H1, nullptr, 0, Wf2, norm, YAb, YBt, YC8, N, 2);
  k_propA<<<PB, 256, 0, stream>>>(YC8, YBt, offs, csr_srcnode, norm, Qt8, N);
  k_propB<<<PB, 256, 0, stream>>>(Qt8, YAb, b2, offs, csr_srcnode, norm, H2, N);

  // readout
  k_colsum<<<256, 128, 0, stream>>>(H2, hg, N);
  k_final<<<1, 128, 0, stream>>>(hg, Wp, bp, (float*)d_out, 1.0f / (float)N);
}

// Round 15
// 851.387 us; speedup vs baseline: 1.0673x; 1.0673x over previous
//
#include <hip/hip_runtime.h>
#include <hip/hip_bf16.h>

// ---------------------------------------------------------------------------
// graphNN round 15 (= R13 + conflict-free LDS staging):
//  - R14 persistent k_edge reverted (2 blocks/CU barrier serialization lost
//    more than the traffic saved; per-tile schedule wins)
//  - X-staging re-mapped: thread t writes slot t (contiguous ds_write_b128,
//    zero bank conflicts; old layout was 8-way on the octet stride).
//    LDS contents bit-identical -> absmax unchanged (2.93e-3 margin kept).
// ---------------------------------------------------------------------------

typedef __attribute__((ext_vector_type(8))) short short8;
typedef __attribute__((ext_vector_type(4))) float f32x4;
typedef __attribute__((ext_vector_type(4))) unsigned u32x4;
typedef unsigned short ushort_t;
typedef unsigned char uchar_t;

static __device__ __forceinline__ unsigned short f2bf(float x) {
  union { float f; unsigned u; } v{x};
  unsigned r = v.u + 0x7FFF + ((v.u >> 16) & 1);
  return (unsigned short)(r >> 16);
}
static __device__ __forceinline__ float bf2f(unsigned short h) {
  union { unsigned u; float f; } v{(unsigned)h << 16};
  return v.f;
}
static __device__ __forceinline__ float u2f(unsigned u) {
  union { unsigned u; float f; } v{u};
  return v.f;
}
static __device__ __forceinline__ unsigned cvtpk(float a, float b) {
  unsigned r;
  asm("v_cvt_pk_bf16_f32 %0, %1, %2" : "=v"(r) : "v"(a), "v"(b));
  return r;
}
static __device__ __forceinline__ uchar_t f2fp8(float x) {
  return (uchar_t)(__builtin_amdgcn_cvt_pk_fp8_f32(x, 0.f, 0, false) & 0xff);
}
static __device__ __forceinline__ ushort_t pk2fp8(float a, float b) {
  return (ushort_t)(__builtin_amdgcn_cvt_pk_fp8_f32(a, b, 0, false) & 0xffff);
}

// ---------- fused init: deg histogram (blocks 0..1023) + weight prep --------
__global__ void k_init(const int* __restrict__ dst, int* __restrict__ deg, int E,
                       const float* __restrict__ msg_W, const float* __restrict__ W1,
                       const float* __restrict__ W2, ushort_t* __restrict__ WfT,
                       ushort_t* __restrict__ WfB, ushort_t* __restrict__ Wf1,
                       ushort_t* __restrict__ Wf2) {
  if (blockIdx.x < 1024) {
    int i = blockIdx.x * 256 + threadIdx.x;
    int stride = 1024 * 256;
    for (; i < E; i += stride) atomicAdd(&deg[dst[i]], 1);
    return;
  }
  int id = (blockIdx.x - 1024) * 256 + threadIdx.x;
  const float* W;
  ushort_t* dh;
  int lid;
  if (id < 16384) {  // WfT: KC=2
    W = msg_W; dh = WfT; lid = id;
  } else if (id < 24576) {  // WfB: KC=1
    W = msg_W + 128 * 128; dh = WfB; lid = id - 16384;
  } else if (id < 122880) {  // Wf1: 3 slices, KC=4
    int sub = id - 24576;
    int s = sub >> 15;
    lid = sub & 32767;
    W = W1 + (size_t)s * 256 * 128;
    dh = Wf1 + (size_t)s * 32768;
  } else if (id < 172032) {  // Wf2: 3 slices, KC=2
    int sub = id - 122880;
    int s = sub >> 14;
    lid = sub & 16383;
    W = W2 + (size_t)s * 128 * 128;
    dh = Wf2 + (size_t)s * 16384;
  } else {
    return;
  }
  int j = lid & 7;
  int l = (lid >> 3) & 63;
  int rest = lid >> 9;
  int ks = rest & 1, nt = (rest >> 1) & 7, kc = rest >> 4;
  int k = kc * 64 + ks * 32 + (l >> 4) * 8 + j;
  int col = nt * 16 + (l & 15);
  dh[lid] = f2bf(W[(size_t)k * 128 + col]);
}

// ---------- CSR fill ----------
__global__ void k_csr(const int* __restrict__ src, const int* __restrict__ dst,
                      int* __restrict__ cursor, int* __restrict__ csr_srcnode,
                      int* __restrict__ csr_eid, int* __restrict__ pos2node, int E) {
  int i = blockIdx.x * blockDim.x + threadIdx.x;
  int stride = gridDim.x * blockDim.x;
  for (; i < E; i += stride) {
    int d = dst[i];
    int pos = atomicAdd(&cursor[d], 1);
    csr_srcnode[pos] = src[i];
    csr_eid[pos] = i;
    pos2node[pos] = d;
  }
}

// ---------- conflict-free A staging (256 threads, 512 slots, fp32 src) ------
// thread t writes slots {t, t+256} (contiguous b128). slot s -> row, octet.
static __device__ __forceinline__ void stage_hi2(
    const float* __restrict__ A0, const float* __restrict__ A1, int split64,
    int kc, int m0, int M, int t, ushort_t* Xh) {
#pragma unroll
  for (int ii = 0; ii < 2; ++ii) {
    const int s = t + ii * 256;
    const int row = min(m0 + (s >> 7) * 16 + (s & 15), M - 1);
    const int o = (s >> 4) & 7;
    const float* base = (kc < split64) ? (A0 + (size_t)row * 128 + kc * 64)
                                       : (A1 + (size_t)row * 128 + (kc - split64) * 64);
    const float* p = base + o * 8;
    f32x4 a4 = *(const f32x4*)p;
    f32x4 b4 = *(const f32x4*)(p + 4);
    u32x4 vh;
    vh[0] = cvtpk(a4[0], a4[1]);
    vh[1] = cvtpk(a4[2], a4[3]);
    vh[2] = cvtpk(b4[0], b4[1]);
    vh[3] = cvtpk(b4[2], b4[3]);
    *(u32x4*)(Xh + (size_t)s * 8) = vh;
  }
}

// ---------- fused: block 0 = scan(deg->offs,cursor,norm); rest = Z GEMM -----
__global__ __launch_bounds__(256) void k_scan_mmz(
    const int* __restrict__ deg, float* __restrict__ norm, int* __restrict__ offs,
    int* __restrict__ cursor, int N, const float* __restrict__ A0,
    const ushort_t* __restrict__ Wf, const float* __restrict__ bias,
    uchar_t* __restrict__ outZ8, int KC) {
  __shared__ __align__(16) char lds[24576];
  if (blockIdx.x == 0) {
    int* part = (int*)lds;
    const int t = threadIdx.x;
    const int C = (N + 255) >> 8;
    const int b = t * C, e = min(b + C, N);
    int s = 0;
    for (int i = b; i < e; ++i) s += deg[i];
    part[t] = s;
    __syncthreads();
    for (int ofs = 1; ofs < 256; ofs <<= 1) {
      int v = (t >= ofs) ? part[t - ofs] : 0;
      __syncthreads();
      part[t] += v;
      __syncthreads();
    }
    int base = (t == 0) ? 0 : part[t - 1];
    for (int i = b; i < e; ++i) {
      offs[i] = base;
      cursor[i] = base;
      int d = deg[i];
      base += d;
      norm[i] = rsqrtf((float)max(d, 1));
    }
    if (t == 0) offs[N] = part[255];
    return;
  }
  ushort_t* Xh = (ushort_t*)lds;            // 8KB
  ushort_t* Whi = (ushort_t*)(lds + 8192);  // 16KB
  const int t = threadIdx.x;
  const int m0 = (blockIdx.x - 1) * 64;
  const int l = t & 63, mt = t >> 6;

  f32x4 acc[8];
#pragma unroll
  for (int nt = 0; nt < 8; ++nt) acc[nt] = (f32x4){0.f, 0.f, 0.f, 0.f};

  for (int kc = 0; kc < KC; ++kc) {
    __syncthreads();
    {
      const ulong2* gh = (const ulong2*)(Wf + (size_t)kc * 8192);
#pragma unroll
      for (int i = 0; i < 4; ++i) ((ulong2*)Whi)[i * 256 + t] = gh[i * 256 + t];
    }
    stage_hi2(A0, A0, KC, kc, m0, N, t, Xh);
    __syncthreads();
    const short8* Xh8 = (const short8*)Xh;
    const short8* Wh8 = (const short8*)Whi;
#pragma unroll
    for (int ks = 0; ks < 2; ++ks) {
      short8 ah = Xh8[mt * 128 + ks * 64 + l];
#pragma unroll
      for (int nt = 0; nt < 8; ++nt)
        acc[nt] = __builtin_amdgcn_mfma_f32_16x16x32_bf16(
            ah, Wh8[(nt * 2 + ks) * 64 + l], acc[nt], 0, 0, 0);
    }
  }
  const int l15 = l & 15, lh = l >> 4;
#pragma unroll
  for (int nt = 0; nt < 8; ++nt) {
    const int col = nt * 16 + l15;
#pragma unroll
    for (int rg = 0; rg < 4; ++rg) {
      const int r = m0 + mt * 16 + lh * 4 + rg;
      if (r < N) outZ8[(size_t)r * 128 + col] = f2fp8(acc[nt][rg] + bias[col]);
    }
  }
}

// ---------- fused 3-slice GEMM: YA bf16, YBt bf16, YC8 fp8 ------------------
template <int BF16A>
__global__ __launch_bounds__(256) void k_mm3(
    const void* __restrict__ A0v, const float* __restrict__ A1, int split64,
    const ushort_t* __restrict__ Wf, const float* __restrict__ rowscale,
    ushort_t* __restrict__ outYA, ushort_t* __restrict__ outYB,
    uchar_t* __restrict__ outYC8, int M, int KC) {
  __shared__ __align__(16) char lds[24576];
  ushort_t* Xh = (ushort_t*)lds;            // 8KB
  ushort_t* Whi = (ushort_t*)(lds + 8192);  // 16KB

  const int t = threadIdx.x;
  const int m0 = blockIdx.x * 64;
  const int l = t & 63, mt = t >> 6;

  f32x4 acc[3][8];
#pragma unroll
  for (int s = 0; s < 3; ++s)
#pragma unroll
    for (int nt = 0; nt < 8; ++nt) acc[s][nt] = (f32x4){0.f, 0.f, 0.f, 0.f};

  for (int kc = 0; kc < KC; ++kc) {
    __syncthreads();
    if constexpr (BF16A) {
#pragma unroll
      for (int ii = 0; ii < 2; ++ii) {
        const int s = t + ii * 256;
        const int row = min(m0 + (s >> 7) * 16 + (s & 15), M - 1);
        const int o = (s >> 4) & 7;
        short8 v = *(const short8*)((const ushort_t*)A0v + (size_t)row * 128 +
                                    kc * 64 + o * 8);
        *(short8*)(Xh + (size_t)s * 8) = v;
      }
    } else {
      stage_hi2((const float*)A0v, A1, split64, kc, m0, M, t, Xh);
    }
#pragma unroll
    for (int s = 0; s < 3; ++s) {
      if (s) __syncthreads();
      {
        const ulong2* gh = (const ulong2*)(Wf + ((size_t)s * KC + kc) * 8192);
#pragma unroll
        for (int i = 0; i < 4; ++i) ((ulong2*)Whi)[i * 256 + t] = gh[i * 256 + t];
      }
      __syncthreads();
      const short8* Xh8 = (const short8*)Xh;
      const short8* Wh8 = (const short8*)Whi;
#pragma unroll
      for (int ks = 0; ks < 2; ++ks) {
        short8 ah = Xh8[mt * 128 + ks * 64 + l];
#pragma unroll
        for (int nt = 0; nt < 8; ++nt)
          acc[s][nt] = __builtin_amdgcn_mfma_f32_16x16x32_bf16(
              ah, Wh8[(nt * 2 + ks) * 64 + l], acc[s][nt], 0, 0, 0);
      }
    }
  }
  const int l15 = l & 15, lh = l >> 4;
#pragma unroll
  for (int rg = 0; rg < 4; ++rg) {
    const int r = m0 + mt * 16 + lh * 4 + rg;
    if (r < M) {
      const float rs = rowscale[r];
#pragma unroll
      for (int nt = 0; nt < 8; ++nt) {
        const int col = nt * 16 + l15;
        outYA[(size_t)r * 128 + col] = f2bf(acc[0][nt][rg]);
        outYB[(size_t)r * 128 + col] = f2bf(acc[1][nt][rg] * rs);
        outYC8[(size_t)r * 128 + col] = f2fp8(acc[2][nt][rg] * rs);
      }
    }
  }
}

// ---------- edge GEMM: 128 edges/block, 1024 threads, conflict-free staging -
__global__ __launch_bounds__(1024, 8) void k_edge(
    const float* __restrict__ ef, const int* __restrict__ csr_srcnode,
    const int* __restrict__ csr_eid, const int* __restrict__ pos2node,
    const ushort_t* __restrict__ WfB, const uchar_t* __restrict__ Z8,
    float* __restrict__ h_neigh) {
  __shared__ __align__(16) char lds[33280];
  ushort_t* Xh = (ushort_t*)lds;             // [0,16K)
  ushort_t* Whi = (ushort_t*)(lds + 16384);  // [16K,32K)
  ushort_t* Cs = (ushort_t*)lds;             // overlay [0,32K): 128x128 bf16
  int* sN = (int*)(lds + 32768);             // [32K,32K+512)

  const int t = threadIdx.x;
  const int b0 = blockIdx.x * 128;
  const int l = t & 63, w = t >> 6;          // 16 waves
  const int mt = w >> 1, nh = w & 1;         // M-tile 0..7, N-half
  const int col = t & 127, g = t >> 7;       // 8 walk groups x 16 rows
  const int rbase = b0 + g * 16;

  // ---- Z prefetch (fp8 bytes) ----
  uchar_t z8[16];
#pragma unroll
  for (int i = 0; i < 16; ++i)
    z8[i] = Z8[(size_t)csr_srcnode[rbase + i] * 128 + col];
  // ---- stage W (one 16B per thread, contiguous) ----
  ((ulong2*)Whi)[t] = ((const ulong2*)WfB)[t];
  // ---- stage ef: thread t writes slot t (contiguous b128, no conflicts) ----
  {
    const int srow = (t >> 7) * 16 + (t & 15);  // row within tile
    const int o = (t >> 4) & 7;                 // k-octet
    const int eid = csr_eid[b0 + srow];
    const float* rowp = ef + (size_t)eid * 64 + o * 8;
    f32x4 a4 = __builtin_nontemporal_load((const f32x4*)rowp);
    f32x4 b4 = __builtin_nontemporal_load((const f32x4*)(rowp + 4));
    u32x4 vh;
    vh[0] = cvtpk(a4[0], a4[1]);
    vh[1] = cvtpk(a4[2], a4[3]);
    vh[2] = cvtpk(b4[0], b4[1]);
    vh[3] = cvtpk(b4[2], b4[3]);
    *(u32x4*)(Xh + (size_t)t * 8) = vh;
  }
  __syncthreads();

  f32x4 acc[4];
#pragma unroll
  for (int nt = 0; nt < 4; ++nt) acc[nt] = (f32x4){0.f, 0.f, 0.f, 0.f};
  {
    const short8* Xh8 = (const short8*)Xh;
    const short8* Wh8 = (const short8*)Whi;
#pragma unroll
    for (int ks = 0; ks < 2; ++ks) {
      short8 ah = Xh8[mt * 128 + ks * 64 + l];
#pragma unroll
      for (int nt = 0; nt < 4; ++nt) {
        const int ntg = nh * 4 + nt;
        acc[nt] = __builtin_amdgcn_mfma_f32_16x16x32_bf16(
            ah, Wh8[(ntg * 2 + ks) * 64 + l], acc[nt], 0, 0, 0);
      }
    }
  }
  __syncthreads();
  // ---- preload node ids + C tile to LDS (bank-correct swizzle) ----
  if (t < 128) sN[t] = pos2node[b0 + t];
  const int l15 = l & 15, lh = l >> 4;
#pragma unroll
  for (int nt = 0; nt < 4; ++nt) {
#pragma unroll
    for (int rg = 0; rg < 4; ++rg) {
      const int row = mt * 16 + lh * 4 + rg;
      const int c = nh * 64 + nt * 16 + l15;
      Cs[row * 128 + (c ^ (((row >> 2) & 3) << 4))] = f2bf(acc[nt][rg]);
    }
  }
  __syncthreads();
  // ---- 8-way parallel segment walk (16 rows each) ----
  {
    int node = sN[g * 16];
    float ssum = 0.f;
#pragma unroll
    for (int r = 0; r < 16; ++r) {
      const int rr = g * 16 + r;
      float cz = bf2f(Cs[rr * 128 + (col ^ (((rr >> 2) & 3) << 4))]);
      float zf = __builtin_amdgcn_cvt_f32_fp8((int)z8[r], 0);
      float v = fmaxf(cz + zf, 0.f);
      if (r == 0) {
        ssum = v;
      } else {
        int n2 = sN[rr];
        if (n2 == node) {
          ssum += v;
        } else {
          unsafeAtomicAdd(&h_neigh[(size_t)node * 128 + col], ssum);
          node = n2;
          ssum = v;
        }
      }
    }
    unsafeAtomicAdd(&h_neigh[(size_t)node * 128 + col], ssum);
  }
}

// ---------- propA: Qt8 = fp8(YBt + n^2 * sum YC8[src])  (4-acc ILP) ---------
__global__ __launch_bounds__(256) void k_propA(
    const uchar_t* __restrict__ YC8, const ushort_t* __restrict__ YBt,
    const int* __restrict__ offs, const int* __restrict__ csr_src,
    const float* __restrict__ norm, uchar_t* __restrict__ Qt8, int N) {
  const int v = blockIdx.x * 4 + (threadIdx.x >> 6);
  const int lane = threadIdx.x & 63;
  if (v >= N) return;
  const int b = offs[v], e = offs[v + 1];
  const ushort_t* yc = (const ushort_t*)YC8;
  float ax0 = 0.f, ay0 = 0.f, ax1 = 0.f, ay1 = 0.f;
  float ax2 = 0.f, ay2 = 0.f, ax3 = 0.f, ay3 = 0.f;
  int i = b;
  const int e4 = b + ((e - b) & ~3);
  for (; i < e4; i += 4) {
    const int s0 = csr_src[i], s1 = csr_src[i + 1];
    const int s2 = csr_src[i + 2], s3 = csr_src[i + 3];
    const int x0 = yc[(size_t)s0 * 64 + lane];
    const int x1 = yc[(size_t)s1 * 64 + lane];
    const int x2 = yc[(size_t)s2 * 64 + lane];
    const int x3 = yc[(size_t)s3 * 64 + lane];
    auto d0 = __builtin_amdgcn_cvt_pk_f32_fp8(x0, false);
    auto d1 = __builtin_amdgcn_cvt_pk_f32_fp8(x1, false);
    auto d2 = __builtin_amdgcn_cvt_pk_f32_fp8(x2, false);
    auto d3 = __builtin_amdgcn_cvt_pk_f32_fp8(x3, false);
    ax0 += d0[0]; ay0 += d0[1];
    ax1 += d1[0]; ay1 += d1[1];
    ax2 += d2[0]; ay2 += d2[1];
    ax3 += d3[0]; ay3 += d3[1];
  }
  for (; i < e; ++i) {
    const int x = yc[(size_t)csr_src[i] * 64 + lane];
    auto d = __builtin_amdgcn_cvt_pk_f32_fp8(x, false);
    ax0 += d[0]; ay0 += d[1];
  }
  const float ax = (ax0 + ax1) + (ax2 + ax3);
  const float ay = (ay0 + ay1) + (ay2 + ay3);
  const float n = norm[v];
  const float n2 = n * n;
  const unsigned yb = ((const unsigned*)YBt)[(size_t)v * 64 + lane];
  ((ushort_t*)Qt8)[(size_t)v * 64 + lane] =
      pk2fp8(u2f(yb << 16) + n2 * ax, u2f(yb & 0xffff0000u) + n2 * ay);
}

// ---------- propB: H = bf16(relu(YA + n * sum Qt8[src] + b)) ----------------
__global__ __launch_bounds__(256) void k_propB(
    const uchar_t* __restrict__ Qt8, const ushort_t* __restrict__ YAb,
    const float* __restrict__ bias, const int* __restrict__ offs,
    const int* __restrict__ csr_src, const float* __restrict__ norm,
    ushort_t* __restrict__ H, int N) {
  const int v = blockIdx.x * 4 + (threadIdx.x >> 6);
  const int lane = threadIdx.x & 63;
  if (v >= N) return;
  const int b = offs[v], e = offs[v + 1];
  const ushort_t* qp = (const ushort_t*)Qt8;
  float ax0 = 0.f, ay0 = 0.f, ax1 = 0.f, ay1 = 0.f;
  float ax2 = 0.f, ay2 = 0.f, ax3 = 0.f, ay3 = 0.f;
  int i = b;
  const int e4 = b + ((e - b) & ~3);
  for (; i < e4; i += 4) {
    const int s0 = csr_src[i], s1 = csr_src[i + 1];
    const int s2 = csr_src[i + 2], s3 = csr_src[i + 3];
    const int x0 = qp[(size_t)s0 * 64 + lane];
    const int x1 = qp[(size_t)s1 * 64 + lane];
    const int x2 = qp[(size_t)s2 * 64 + lane];
    const int x3 = qp[(size_t)s3 * 64 + lane];
    auto d0 = __builtin_amdgcn_cvt_pk_f32_fp8(x0, false);
    auto d1 = __builtin_amdgcn_cvt_pk_f32_fp8(x1, false);
    auto d2 = __builtin_amdgcn_cvt_pk_f32_fp8(x2, false);
    auto d3 = __builtin_amdgcn_cvt_pk_f32_fp8(x3, false);
    ax0 += d0[0]; ay0 += d0[1];
    ax1 += d1[0]; ay1 += d1[1];
    ax2 += d2[0]; ay2 += d2[1];
    ax3 += d3[0]; ay3 += d3[1];
  }
  for (; i < e; ++i) {
    const int x = qp[(size_t)csr_src[i] * 64 + lane];
    auto d = __builtin_amdgcn_cvt_pk_f32_fp8(x, false);
    ax0 += d[0]; ay0 += d[1];
  }
  const float ax = (ax0 + ax1) + (ax2 + ax3);
  const float ay = (ay0 + ay1) + (ay2 + ay3);
  const float n = norm[v];
  const unsigned ya = ((const unsigned*)YAb)[(size_t)v * 64 + lane];
  const float2 bb = ((const float2*)bias)[lane];
  const float hx = fmaxf(u2f(ya << 16) + n * ax + bb.x, 0.f);
  const float hy = fmaxf(u2f(ya & 0xffff0000u) + n * ay + bb.y, 0.f);
  ((unsigned*)H)[(size_t)v * 64 + lane] = cvtpk(hx, hy);
}

// ---------- column sums of bf16 h -> hg[128] ----------
__global__ void k_colsum(const ushort_t* __restrict__ h, float* __restrict__ hg, int N) {
  const int t = threadIdx.x;  // 128
  const int per = (N + gridDim.x - 1) / gridDim.x;
  const int n0 = blockIdx.x * per, n1 = min(n0 + per, N);
  float s = 0.f;
  for (int n = n0; n < n1; ++n) s += bf2f(h[(size_t)n * 128 + t]);
  unsafeAtomicAdd(&hg[t], s);
}

// ---------- final ----------
__global__ void k_final(const float* __restrict__ hg, const float* __restrict__ Wp,
                        const float* __restrict__ bp, float* __restrict__ out,
                        float invN) {
  __shared__ float red[128];
  const int t = threadIdx.x;
  red[t] = hg[t] * invN * Wp[t];
  __syncthreads();
  for (int s = 64; s > 0; s >>= 1) {
    if (t < s) red[t] += red[t + s];
    __syncthreads();
  }
  if (t == 0) out[0] = red[0] + bp[0];
}

extern "C" void kernel_launch(void* const* d_in, const int* in_sizes, int n_in,
                              void* d_out, int out_size, void* d_ws, size_t ws_size,
                              hipStream_t stream) {
  const float* node_fea = (const float*)d_in[0];
  const float* edge_fea = (const float*)d_in[1];
  const int* src = (const int*)d_in[2];
  const int* dst = (const int*)d_in[3];
  const float* msg_W = (const float*)d_in[4];
  const float* msg_b = (const float*)d_in[5];
  const float* W1 = (const float*)d_in[6];
  const float* b1 = (const float*)d_in[7];
  const float* W2 = (const float*)d_in[8];
  const float* b2 = (const float*)d_in[9];
  const float* Wp = (const float*)d_in[10];
  const float* bp = (const float*)d_in[11];

  const int N = in_sizes[0] / 128;  // 50000
  const int E = in_sizes[2];        // 1600000

  char* p = (char*)d_ws;
  auto alloc = [&](size_t bytes) {
    char* r = p;
    p += (bytes + 255) & ~(size_t)255;
    return r;
  };
  int* deg = (int*)alloc((size_t)N * 4);
  float* norm = (float*)alloc((size_t)N * 4);
  int* offs = (int*)alloc((size_t)(N + 1) * 4);
  int* cursor = (int*)alloc((size_t)N * 4);
  int* csr_srcnode = (int*)alloc((size_t)E * 4);
  int* csr_eid = (int*)alloc((size_t)E * 4);
  int* pos2node = (int*)alloc((size_t)E * 4);
  ushort_t* WfT = (ushort_t*)alloc(2 * 8192 * 2);
  ushort_t* WfB = (ushort_t*)alloc(1 * 8192 * 2);
  ushort_t* Wf1 = (ushort_t*)alloc(3 * 4 * 8192 * 2);
  ushort_t* Wf2 = (ushort_t*)alloc(3 * 2 * 8192 * 2);
  uchar_t* Z8 = (uchar_t*)alloc((size_t)N * 128);         // fp8 Z
  ushort_t* YAb = (ushort_t*)alloc((size_t)N * 128 * 2);  // bf16 YA
  float* hn = (float*)alloc((size_t)N * 128 * 4);
  ushort_t* YBt = (ushort_t*)alloc((size_t)N * 128 * 2);  // bf16 (streamed)
  uchar_t* YC8 = (uchar_t*)alloc((size_t)N * 128);        // fp8 (gathered)
  uchar_t* Qt8 = (uchar_t*)alloc((size_t)N * 128);        // fp8 (gathered)
  ushort_t* H1 = (ushort_t*)alloc((size_t)N * 128 * 2);
  ushort_t* H2 = (ushort_t*)alloc((size_t)N * 128 * 2);
  float* hg = (float*)alloc(128 * 4);

  (void)hipMemsetAsync(deg, 0, (size_t)N * 4, stream);
  (void)hipMemsetAsync(hn, 0, (size_t)N * 128 * 4, stream);
  (void)hipMemsetAsync(hg, 0, 128 * 4, stream);

  // fused: deg histogram + all weight prep
  k_init<<<1696, 256, 0, stream>>>(dst, deg, E, msg_W, W1, W2, WfT, WfB, Wf1, Wf2);

  const int MB = (N + 63) / 64;  // 782
  const int PB = (N + 3) / 4;

  // fused: scan (block 0) + Z = node_fea @ W_top + b (blocks 1..MB)
  k_scan_mmz<<<MB + 1, 256, 0, stream>>>(deg, norm, offs, cursor, N, node_fea,
                                         WfT, msg_b, Z8, 2);
  // CSR fill
  k_csr<<<2048, 256, 0, stream>>>(src, dst, cursor, csr_srcnode, csr_eid, pos2node, E);
  // edge messages -> hn
  k_edge<<<E / 128, 1024, 0, stream>>>(edge_fea, csr_srcnode, csr_eid, pos2node,
                                       WfB, Z8, hn);

  // ----- layer 1: A = [node_fea | hn] fp32, K=256 -----
  k_mm3<0><<<MB, 256, 0, stream>>>(node_fea, hn, 2, Wf1, norm, YAb, YBt, YC8, N, 4);
  k_propA<<<PB, 256, 0, stream>>>(YC8, YBt, offs, csr_srcnode, norm, Qt8, N);
  k_propB<<<PB, 256, 0, stream>>>(Qt8, YAb, b1, offs, csr_srcnode, norm, H1, N);

  // ----- layer 2: A = H1 bf16, K=128 -----
  k_mm3<1><<<MB, 256, 0, stream>>>(H1, nullptr, 0, Wf2, norm, YAb, YBt, YC8, N, 2);
  k_propA<<<PB, 256, 0, stream>>>(YC8, YBt, offs, csr_srcnode, norm, Qt8, N);
  k_propB<<<PB, 256, 0, stream>>>(Qt8, YAb, b2, offs, csr_srcnode, norm, H2, N);

  // readout
  k_colsum<<<256, 128, 0, stream>>>(H2, hg, N);
  k_final<<<1, 128, 0, stream>>>(hg, Wp, bp, (float*)d_out, 1.0f / (float)N);
}

// Round 16
// 825.626 us; speedup vs baseline: 1.1006x; 1.0312x over previous
//
#include <hip/hip_runtime.h>
#include <hip/hip_bf16.h>

// ---------------------------------------------------------------------------
// graphNN round 16 (= R13 + k_edge retiled 64 edges x 512 threads):
//  - R13 was best (833us). R14 persistent (2 blk/CU barrier serial) and R15
//    staging remap (broke global coalescing) both failed vs it.
//  - k_edge: 8 waves/block -> 4 blocks/CU (was wave-capped at 2 with 1024thr);
//    3 sibling blocks cover each barrier; Z-prefetch chain overlaps 4x tiles.
//  - all arithmetic identical to R13 (absmax 2.93e-3 margin preserved)
// ---------------------------------------------------------------------------

typedef __attribute__((ext_vector_type(8))) short short8;
typedef __attribute__((ext_vector_type(4))) float f32x4;
typedef __attribute__((ext_vector_type(4))) unsigned u32x4;
typedef unsigned short ushort_t;
typedef unsigned char uchar_t;

static __device__ __forceinline__ unsigned short f2bf(float x) {
  union { float f; unsigned u; } v{x};
  unsigned r = v.u + 0x7FFF + ((v.u >> 16) & 1);
  return (unsigned short)(r >> 16);
}
static __device__ __forceinline__ float bf2f(unsigned short h) {
  union { unsigned u; float f; } v{(unsigned)h << 16};
  return v.f;
}
static __device__ __forceinline__ float u2f(unsigned u) {
  union { unsigned u; float f; } v{u};
  return v.f;
}
static __device__ __forceinline__ unsigned cvtpk(float a, float b) {
  unsigned r;
  asm("v_cvt_pk_bf16_f32 %0, %1, %2" : "=v"(r) : "v"(a), "v"(b));
  return r;
}
static __device__ __forceinline__ uchar_t f2fp8(float x) {
  return (uchar_t)(__builtin_amdgcn_cvt_pk_fp8_f32(x, 0.f, 0, false) & 0xff);
}
static __device__ __forceinline__ ushort_t pk2fp8(float a, float b) {
  return (ushort_t)(__builtin_amdgcn_cvt_pk_fp8_f32(a, b, 0, false) & 0xffff);
}

// ---------- fused init: deg histogram (blocks 0..1023) + weight prep --------
__global__ void k_init(const int* __restrict__ dst, int* __restrict__ deg, int E,
                       const float* __restrict__ msg_W, const float* __restrict__ W1,
                       const float* __restrict__ W2, ushort_t* __restrict__ WfT,
                       ushort_t* __restrict__ WfB, ushort_t* __restrict__ Wf1,
                       ushort_t* __restrict__ Wf2) {
  if (blockIdx.x < 1024) {
    int i = blockIdx.x * 256 + threadIdx.x;
    int stride = 1024 * 256;
    for (; i < E; i += stride) atomicAdd(&deg[dst[i]], 1);
    return;
  }
  int id = (blockIdx.x - 1024) * 256 + threadIdx.x;
  const float* W;
  ushort_t* dh;
  int lid;
  if (id < 16384) {  // WfT: KC=2
    W = msg_W; dh = WfT; lid = id;
  } else if (id < 24576) {  // WfB: KC=1
    W = msg_W + 128 * 128; dh = WfB; lid = id - 16384;
  } else if (id < 122880) {  // Wf1: 3 slices, KC=4
    int sub = id - 24576;
    int s = sub >> 15;
    lid = sub & 32767;
    W = W1 + (size_t)s * 256 * 128;
    dh = Wf1 + (size_t)s * 32768;
  } else if (id < 172032) {  // Wf2: 3 slices, KC=2
    int sub = id - 122880;
    int s = sub >> 14;
    lid = sub & 16383;
    W = W2 + (size_t)s * 128 * 128;
    dh = Wf2 + (size_t)s * 16384;
  } else {
    return;
  }
  int j = lid & 7;
  int l = (lid >> 3) & 63;
  int rest = lid >> 9;
  int ks = rest & 1, nt = (rest >> 1) & 7, kc = rest >> 4;
  int k = kc * 64 + ks * 32 + (l >> 4) * 8 + j;
  int col = nt * 16 + (l & 15);
  dh[lid] = f2bf(W[(size_t)k * 128 + col]);
}

// ---------- CSR fill ----------
__global__ void k_csr(const int* __restrict__ src, const int* __restrict__ dst,
                      int* __restrict__ cursor, int* __restrict__ csr_srcnode,
                      int* __restrict__ csr_eid, int* __restrict__ pos2node, int E) {
  int i = blockIdx.x * blockDim.x + threadIdx.x;
  int stride = gridDim.x * blockDim.x;
  for (; i < E; i += stride) {
    int d = dst[i];
    int pos = atomicAdd(&cursor[d], 1);
    csr_srcnode[pos] = src[i];
    csr_eid[pos] = i;
    pos2node[pos] = d;
  }
}

// stage 16 fp32 -> bf16-hi LDS fragment slots (R13 layout: coalesced reads)
static __device__ __forceinline__ void stage_hi(const float* base, int sq, int sr,
                                                ushort_t* Xh) {
#pragma unroll
  for (int i2 = 0; i2 < 2; ++i2) {
    const int o = sq * 2 + i2;
    f32x4 a4 = *(const f32x4*)(base + sq * 16 + i2 * 8);
    f32x4 b4 = *(const f32x4*)(base + sq * 16 + i2 * 8 + 4);
    u32x4 vh;
    vh[0] = cvtpk(a4[0], a4[1]);
    vh[1] = cvtpk(a4[2], a4[3]);
    vh[2] = cvtpk(b4[0], b4[1]);
    vh[3] = cvtpk(b4[2], b4[3]);
    const int slot = (sr >> 4) * 128 + o * 16 + (sr & 15);
    *(u32x4*)(Xh + (size_t)slot * 8) = vh;
  }
}

// ---------- fused: block 0 = scan(deg->offs,cursor,norm); rest = Z GEMM -----
__global__ __launch_bounds__(256) void k_scan_mmz(
    const int* __restrict__ deg, float* __restrict__ norm, int* __restrict__ offs,
    int* __restrict__ cursor, int N, const float* __restrict__ A0,
    const ushort_t* __restrict__ Wf, const float* __restrict__ bias,
    uchar_t* __restrict__ outZ8, int KC) {
  __shared__ __align__(16) char lds[24576];
  if (blockIdx.x == 0) {
    int* part = (int*)lds;
    const int t = threadIdx.x;
    const int C = (N + 255) >> 8;
    const int b = t * C, e = min(b + C, N);
    int s = 0;
    for (int i = b; i < e; ++i) s += deg[i];
    part[t] = s;
    __syncthreads();
    for (int ofs = 1; ofs < 256; ofs <<= 1) {
      int v = (t >= ofs) ? part[t - ofs] : 0;
      __syncthreads();
      part[t] += v;
      __syncthreads();
    }
    int base = (t == 0) ? 0 : part[t - 1];
    for (int i = b; i < e; ++i) {
      offs[i] = base;
      cursor[i] = base;
      int d = deg[i];
      base += d;
      norm[i] = rsqrtf((float)max(d, 1));
    }
    if (t == 0) offs[N] = part[255];
    return;
  }
  ushort_t* Xh = (ushort_t*)lds;            // 8KB
  ushort_t* Whi = (ushort_t*)(lds + 8192);  // 16KB
  const int t = threadIdx.x;
  const int m0 = (blockIdx.x - 1) * 64;
  const int l = t & 63, mt = t >> 6;
  const int sr = t & 63, sq = t >> 6;
  const int row = min(m0 + sr, N - 1);

  f32x4 acc[8];
#pragma unroll
  for (int nt = 0; nt < 8; ++nt) acc[nt] = (f32x4){0.f, 0.f, 0.f, 0.f};

  for (int kc = 0; kc < KC; ++kc) {
    __syncthreads();
    {
      const ulong2* gh = (const ulong2*)(Wf + (size_t)kc * 8192);
#pragma unroll
      for (int i = 0; i < 4; ++i) ((ulong2*)Whi)[i * 256 + t] = gh[i * 256 + t];
    }
    stage_hi(A0 + (size_t)row * 128 + kc * 64, sq, sr, Xh);
    __syncthreads();
    const short8* Xh8 = (const short8*)Xh;
    const short8* Wh8 = (const short8*)Whi;
#pragma unroll
    for (int ks = 0; ks < 2; ++ks) {
      short8 ah = Xh8[mt * 128 + ks * 64 + l];
#pragma unroll
      for (int nt = 0; nt < 8; ++nt)
        acc[nt] = __builtin_amdgcn_mfma_f32_16x16x32_bf16(
            ah, Wh8[(nt * 2 + ks) * 64 + l], acc[nt], 0, 0, 0);
    }
  }
  const int l15 = l & 15, lh = l >> 4;
#pragma unroll
  for (int nt = 0; nt < 8; ++nt) {
    const int col = nt * 16 + l15;
#pragma unroll
    for (int rg = 0; rg < 4; ++rg) {
      const int r = m0 + mt * 16 + lh * 4 + rg;
      if (r < N) outZ8[(size_t)r * 128 + col] = f2fp8(acc[nt][rg] + bias[col]);
    }
  }
}

// ---------- fused 3-slice GEMM: YA bf16, YBt bf16, YC8 fp8 ------------------
template <int BF16A>
__global__ __launch_bounds__(256) void k_mm3(
    const void* __restrict__ A0v, const float* __restrict__ A1, int split64,
    const ushort_t* __restrict__ Wf, const float* __restrict__ rowscale,
    ushort_t* __restrict__ outYA, ushort_t* __restrict__ outYB,
    uchar_t* __restrict__ outYC8, int M, int KC) {
  __shared__ __align__(16) char lds[24576];
  ushort_t* Xh = (ushort_t*)lds;            // 8KB
  ushort_t* Whi = (ushort_t*)(lds + 8192);  // 16KB

  const int t = threadIdx.x;
  const int m0 = blockIdx.x * 64;
  const int l = t & 63, mt = t >> 6;
  const int sr = t & 63, sq = t >> 6;
  const int row = min(m0 + sr, M - 1);

  f32x4 acc[3][8];
#pragma unroll
  for (int s = 0; s < 3; ++s)
#pragma unroll
    for (int nt = 0; nt < 8; ++nt) acc[s][nt] = (f32x4){0.f, 0.f, 0.f, 0.f};

  for (int kc = 0; kc < KC; ++kc) {
    __syncthreads();
    if constexpr (BF16A) {
      const ushort_t* base = (const ushort_t*)A0v + (size_t)row * 128 + kc * 64;
#pragma unroll
      for (int i2 = 0; i2 < 2; ++i2) {
        const int o = sq * 2 + i2;
        short8 v = *(const short8*)(base + sq * 16 + i2 * 8);
        const int slot = (sr >> 4) * 128 + o * 16 + (sr & 15);
        *(short8*)(Xh + (size_t)slot * 8) = v;
      }
    } else {
      const float* A0 = (const float*)A0v;
      const float* base = (kc < split64) ? (A0 + (size_t)row * 128 + kc * 64)
                                         : (A1 + (size_t)row * 128 + (kc - split64) * 64);
      stage_hi(base, sq, sr, Xh);
    }
#pragma unroll
    for (int s = 0; s < 3; ++s) {
      if (s) __syncthreads();
      {
        const ulong2* gh = (const ulong2*)(Wf + ((size_t)s * KC + kc) * 8192);
#pragma unroll
        for (int i = 0; i < 4; ++i) ((ulong2*)Whi)[i * 256 + t] = gh[i * 256 + t];
      }
      __syncthreads();
      const short8* Xh8 = (const short8*)Xh;
      const short8* Wh8 = (const short8*)Whi;
#pragma unroll
      for (int ks = 0; ks < 2; ++ks) {
        short8 ah = Xh8[mt * 128 + ks * 64 + l];
#pragma unroll
        for (int nt = 0; nt < 8; ++nt)
          acc[s][nt] = __builtin_amdgcn_mfma_f32_16x16x32_bf16(
              ah, Wh8[(nt * 2 + ks) * 64 + l], acc[s][nt], 0, 0, 0);
      }
    }
  }
  const int l15 = l & 15, lh = l >> 4;
#pragma unroll
  for (int rg = 0; rg < 4; ++rg) {
    const int r = m0 + mt * 16 + lh * 4 + rg;
    if (r < M) {
      const float rs = rowscale[r];
#pragma unroll
      for (int nt = 0; nt < 8; ++nt) {
        const int col = nt * 16 + l15;
        outYA[(size_t)r * 128 + col] = f2bf(acc[0][nt][rg]);
        outYB[(size_t)r * 128 + col] = f2bf(acc[1][nt][rg] * rs);
        outYC8[(size_t)r * 128 + col] = f2fp8(acc[2][nt][rg] * rs);
      }
    }
  }
}

// ---------- edge GEMM: 64 edges/block, 512 threads (8 waves, 4 blk/CU) ------
// LDS: W[0,16K) | X[16K,24K) | C overlay [16K,32K): 64x128 bf16 | sN [32K,+256)
__global__ __launch_bounds__(512, 8) void k_edge(
    const float* __restrict__ ef, const int* __restrict__ csr_srcnode,
    const int* __restrict__ csr_eid, const int* __restrict__ pos2node,
    const ushort_t* __restrict__ WfB, const uchar_t* __restrict__ Z8,
    float* __restrict__ h_neigh) {
  __shared__ __align__(16) char lds[33024];
  ushort_t* Whi = (ushort_t*)lds;            // [0,16K)
  ushort_t* Xh = (ushort_t*)(lds + 16384);   // [16K,24K)
  ushort_t* Cs = (ushort_t*)(lds + 16384);   // overlay [16K,32K)
  int* sN = (int*)(lds + 32768);             // [32K,+256)

  const int t = threadIdx.x;
  const int b0 = blockIdx.x * 64;
  const int l = t & 63, w = t >> 6;          // 8 waves
  const int mt = w >> 1, nh = w & 1;         // M-tile 0..3, N-half
  const int col = t & 127, g = t >> 7;       // 4 walk groups x 16 rows
  const int rbase = b0 + g * 16;

  // ---- Z prefetch (fp8 bytes) ----
  uchar_t z8[16];
#pragma unroll
  for (int i = 0; i < 16; ++i)
    z8[i] = Z8[(size_t)csr_srcnode[rbase + i] * 128 + col];
  // ---- stage W (two 16B per thread, contiguous) ----
  ((ulong2*)Whi)[t] = ((const ulong2*)WfB)[t];
  ((ulong2*)Whi)[t + 512] = ((const ulong2*)WfB)[t + 512];
  // ---- stage ef rows: 8 threads/row (coalesced 256B/row) ----
  {
    const int row = t >> 3, part = t & 7;
    const int eid = csr_eid[b0 + row];
    const float* rowp = ef + (size_t)eid * 64 + part * 8;
    f32x4 a4 = __builtin_nontemporal_load((const f32x4*)rowp);
    f32x4 b4 = __builtin_nontemporal_load((const f32x4*)(rowp + 4));
    u32x4 vh;
    vh[0] = cvtpk(a4[0], a4[1]);
    vh[1] = cvtpk(a4[2], a4[3]);
    vh[2] = cvtpk(b4[0], b4[1]);
    vh[3] = cvtpk(b4[2], b4[3]);
    const int slot = (row >> 4) * 128 + part * 16 + (row & 15);
    *(u32x4*)(Xh + (size_t)slot * 8) = vh;
  }
  __syncthreads();

  f32x4 acc[4];
#pragma unroll
  for (int nt = 0; nt < 4; ++nt) acc[nt] = (f32x4){0.f, 0.f, 0.f, 0.f};
  {
    const short8* Xh8 = (const short8*)Xh;
    const short8* Wh8 = (const short8*)Whi;
#pragma unroll
    for (int ks = 0; ks < 2; ++ks) {
      short8 ah = Xh8[mt * 128 + ks * 64 + l];
#pragma unroll
      for (int nt = 0; nt < 4; ++nt) {
        const int ntg = nh * 4 + nt;
        acc[nt] = __builtin_amdgcn_mfma_f32_16x16x32_bf16(
            ah, Wh8[(ntg * 2 + ks) * 64 + l], acc[nt], 0, 0, 0);
      }
    }
  }
  __syncthreads();
  // ---- preload node ids + C tile to LDS (bank-correct swizzle) ----
  if (t < 64) sN[t] = pos2node[b0 + t];
  const int l15 = l & 15, lh = l >> 4;
#pragma unroll
  for (int nt = 0; nt < 4; ++nt) {
#pragma unroll
    for (int rg = 0; rg < 4; ++rg) {
      const int row = mt * 16 + lh * 4 + rg;
      const int c = nh * 64 + nt * 16 + l15;
      Cs[row * 128 + (c ^ (((row >> 2) & 3) << 4))] = f2bf(acc[nt][rg]);
    }
  }
  __syncthreads();
  // ---- 4-way parallel segment walk (16 rows each) ----
  {
    int node = sN[g * 16];
    float ssum = 0.f;
#pragma unroll
    for (int r = 0; r < 16; ++r) {
      const int rr = g * 16 + r;
      float cz = bf2f(Cs[rr * 128 + (col ^ (((rr >> 2) & 3) << 4))]);
      float zf = __builtin_amdgcn_cvt_f32_fp8((int)z8[r], 0);
      float v = fmaxf(cz + zf, 0.f);
      if (r == 0) {
        ssum = v;
      } else {
        int n2 = sN[rr];
        if (n2 == node) {
          ssum += v;
        } else {
          unsafeAtomicAdd(&h_neigh[(size_t)node * 128 + col], ssum);
          node = n2;
          ssum = v;
        }
      }
    }
    unsafeAtomicAdd(&h_neigh[(size_t)node * 128 + col], ssum);
  }
}

// ---------- propA: Qt8 = fp8(YBt + n^2 * sum YC8[src])  (4-acc ILP) ---------
__global__ __launch_bounds__(256) void k_propA(
    const uchar_t* __restrict__ YC8, const ushort_t* __restrict__ YBt,
    const int* __restrict__ offs, const int* __restrict__ csr_src,
    const float* __restrict__ norm, uchar_t* __restrict__ Qt8, int N) {
  const int v = blockIdx.x * 4 + (threadIdx.x >> 6);
  const int lane = threadIdx.x & 63;
  if (v >= N) return;
  const int b = offs[v], e = offs[v + 1];
  const ushort_t* yc = (const ushort_t*)YC8;
  float ax0 = 0.f, ay0 = 0.f, ax1 = 0.f, ay1 = 0.f;
  float ax2 = 0.f, ay2 = 0.f, ax3 = 0.f, ay3 = 0.f;
  int i = b;
  const int e4 = b + ((e - b) & ~3);
  for (; i < e4; i += 4) {
    const int s0 = csr_src[i], s1 = csr_src[i + 1];
    const int s2 = csr_src[i + 2], s3 = csr_src[i + 3];
    const int x0 = yc[(size_t)s0 * 64 + lane];
    const int x1 = yc[(size_t)s1 * 64 + lane];
    const int x2 = yc[(size_t)s2 * 64 + lane];
    const int x3 = yc[(size_t)s3 * 64 + lane];
    auto d0 = __builtin_amdgcn_cvt_pk_f32_fp8(x0, false);
    auto d1 = __builtin_amdgcn_cvt_pk_f32_fp8(x1, false);
    auto d2 = __builtin_amdgcn_cvt_pk_f32_fp8(x2, false);
    auto d3 = __builtin_amdgcn_cvt_pk_f32_fp8(x3, false);
    ax0 += d0[0]; ay0 += d0[1];
    ax1 += d1[0]; ay1 += d1[1];
    ax2 += d2[0]; ay2 += d2[1];
    ax3 += d3[0]; ay3 += d3[1];
  }
  for (; i < e; ++i) {
    const int x = yc[(size_t)csr_src[i] * 64 + lane];
    auto d = __builtin_amdgcn_cvt_pk_f32_fp8(x, false);
    ax0 += d[0]; ay0 += d[1];
  }
  const float ax = (ax0 + ax1) + (ax2 + ax3);
  const float ay = (ay0 + ay1) + (ay2 + ay3);
  const float n = norm[v];
  const float n2 = n * n;
  const unsigned yb = ((const unsigned*)YBt)[(size_t)v * 64 + lane];
  ((ushort_t*)Qt8)[(size_t)v * 64 + lane] =
      pk2fp8(u2f(yb << 16) + n2 * ax, u2f(yb & 0xffff0000u) + n2 * ay);
}

// ---------- propB: H = bf16(relu(YA + n * sum Qt8[src] + b)) ----------------
__global__ __launch_bounds__(256) void k_propB(
    const uchar_t* __restrict__ Qt8, const ushort_t* __restrict__ YAb,
    const float* __restrict__ bias, const int* __restrict__ offs,
    const int* __restrict__ csr_src, const float* __restrict__ norm,
    ushort_t* __restrict__ H, int N) {
  const int v = blockIdx.x * 4 + (threadIdx.x >> 6);
  const int lane = threadIdx.x & 63;
  if (v >= N) return;
  const int b = offs[v], e = offs[v + 1];
  const ushort_t* qp = (const ushort_t*)Qt8;
  float ax0 = 0.f, ay0 = 0.f, ax1 = 0.f, ay1 = 0.f;
  float ax2 = 0.f, ay2 = 0.f, ax3 = 0.f, ay3 = 0.f;
  int i = b;
  const int e4 = b + ((e - b) & ~3);
  for (; i < e4; i += 4) {
    const int s0 = csr_src[i], s1 = csr_src[i + 1];
    const int s2 = csr_src[i + 2], s3 = csr_src[i + 3];
    const int x0 = qp[(size_t)s0 * 64 + lane];
    const int x1 = qp[(size_t)s1 * 64 + lane];
    const int x2 = qp[(size_t)s2 * 64 + lane];
    const int x3 = qp[(size_t)s3 * 64 + lane];
    auto d0 = __builtin_amdgcn_cvt_pk_f32_fp8(x0, false);
    auto d1 = __builtin_amdgcn_cvt_pk_f32_fp8(x1, false);
    auto d2 = __builtin_amdgcn_cvt_pk_f32_fp8(x2, false);
    auto d3 = __builtin_amdgcn_cvt_pk_f32_fp8(x3, false);
    ax0 += d0[0]; ay0 += d0[1];
    ax1 += d1[0]; ay1 += d1[1];
    ax2 += d2[0]; ay2 += d2[1];
    ax3 += d3[0]; ay3 += d3[1];
  }
  for (; i < e; ++i) {
    const int x = qp[(size_t)csr_src[i] * 64 + lane];
    auto d = __builtin_amdgcn_cvt_pk_f32_fp8(x, false);
    ax0 += d[0]; ay0 += d[1];
  }
  const float ax = (ax0 + ax1) + (ax2 + ax3);
  const float ay = (ay0 + ay1) + (ay2 + ay3);
  const float n = norm[v];
  const unsigned ya = ((const unsigned*)YAb)[(size_t)v * 64 + lane];
  const float2 bb = ((const float2*)bias)[lane];
  const float hx = fmaxf(u2f(ya << 16) + n * ax + bb.x, 0.f);
  const float hy = fmaxf(u2f(ya & 0xffff0000u) + n * ay + bb.y, 0.f);
  ((unsigned*)H)[(size_t)v * 64 + lane] = cvtpk(hx, hy);
}

// ---------- column sums of bf16 h -> hg[128] ----------
__global__ void k_colsum(const ushort_t* __restrict__ h, float* __restrict__ hg, int N) {
  const int t = threadIdx.x;  // 128
  const int per = (N + gridDim.x - 1) / gridDim.x;
  const int n0 = blockIdx.x * per, n1 = min(n0 + per, N);
  float s = 0.f;
  for (int n = n0; n < n1; ++n) s += bf2f(h[(size_t)n * 128 + t]);
  unsafeAtomicAdd(&hg[t], s);
}

// ---------- final ----------
__global__ void k_final(const float* __restrict__ hg, const float* __restrict__ Wp,
                        const float* __restrict__ bp, float* __restrict__ out,
                        float invN) {
  __shared__ float red[128];
  const int t = threadIdx.x;
  red[t] = hg[t] * invN * Wp[t];
  __syncthreads();
  for (int s = 64; s > 0; s >>= 1) {
    if (t < s) red[t] += red[t + s];
    __syncthreads();
  }
  if (t == 0) out[0] = red[0] + bp[0];
}

extern "C" void kernel_launch(void* const* d_in, const int* in_sizes, int n_in,
                              void* d_out, int out_size, void* d_ws, size_t ws_size,
                              hipStream_t stream) {
  const float* node_fea = (const float*)d_in[0];
  const float* edge_fea = (const float*)d_in[1];
  const int* src = (const int*)d_in[2];
  const int* dst = (const int*)d_in[3];
  const float* msg_W = (const float*)d_in[4];
  const float* msg_b = (const float*)d_in[5];
  const float* W1 = (const float*)d_in[6];
  const float* b1 = (const float*)d_in[7];
  const float* W2 = (const float*)d_in[8];
  const float* b2 = (const float*)d_in[9];
  const float* Wp = (const float*)d_in[10];
  const float* bp = (const float*)d_in[11];

  const int N = in_sizes[0] / 128;  // 50000
  const int E = in_sizes[2];        // 1600000

  char* p = (char*)d_ws;
  auto alloc = [&](size_t bytes) {
    char* r = p;
    p += (bytes + 255) & ~(size_t)255;
    return r;
  };
  int* deg = (int*)alloc((size_t)N * 4);
  float* norm = (float*)alloc((size_t)N * 4);
  int* offs = (int*)alloc((size_t)(N + 1) * 4);
  int* cursor = (int*)alloc((size_t)N * 4);
  int* csr_srcnode = (int*)alloc((size_t)E * 4);
  int* csr_eid = (int*)alloc((size_t)E * 4);
  int* pos2node = (int*)alloc((size_t)E * 4);
  ushort_t* WfT = (ushort_t*)alloc(2 * 8192 * 2);
  ushort_t* WfB = (ushort_t*)alloc(1 * 8192 * 2);
  ushort_t* Wf1 = (ushort_t*)alloc(3 * 4 * 8192 * 2);
  ushort_t* Wf2 = (ushort_t*)alloc(3 * 2 * 8192 * 2);
  uchar_t* Z8 = (uchar_t*)alloc((size_t)N * 128);         // fp8 Z
  ushort_t* YAb = (ushort_t*)alloc((size_t)N * 128 * 2);  // bf16 YA
  float* hn = (float*)alloc((size_t)N * 128 * 4);
  ushort_t* YBt = (ushort_t*)alloc((size_t)N * 128 * 2);  // bf16 (streamed)
  uchar_t* YC8 = (uchar_t*)alloc((size_t)N * 128);        // fp8 (gathered)
  uchar_t* Qt8 = (uchar_t*)alloc((size_t)N * 128);        // fp8 (gathered)
  ushort_t* H1 = (ushort_t*)alloc((size_t)N * 128 * 2);
  ushort_t* H2 = (ushort_t*)alloc((size_t)N * 128 * 2);
  float* hg = (float*)alloc(128 * 4);

  (void)hipMemsetAsync(deg, 0, (size_t)N * 4, stream);
  (void)hipMemsetAsync(hn, 0, (size_t)N * 128 * 4, stream);
  (void)hipMemsetAsync(hg, 0, 128 * 4, stream);

  // fused: deg histogram + all weight prep
  k_init<<<1696, 256, 0, stream>>>(dst, deg, E, msg_W, W1, W2, WfT, WfB, Wf1, Wf2);

  const int MB = (N + 63) / 64;  // 782
  const int PB = (N + 3) / 4;

  // fused: scan (block 0) + Z = node_fea @ W_top + b (blocks 1..MB)
  k_scan_mmz<<<MB + 1, 256, 0, stream>>>(deg, norm, offs, cursor, N, node_fea,
                                         WfT, msg_b, Z8, 2);
  // CSR fill
  k_csr<<<2048, 256, 0, stream>>>(src, dst, cursor, csr_srcnode, csr_eid, pos2node, E);
  // edge messages -> hn (64 edges/block, 512 threads, 4 blocks/CU)
  k_edge<<<E / 64, 512, 0, stream>>>(edge_fea, csr_srcnode, csr_eid, pos2node,
                                     WfB, Z8, hn);

  // ----- layer 1: A = [node_fea | hn] fp32, K=256 -----
  k_mm3<0><<<MB, 256, 0, stream>>>(node_fea, hn, 2, Wf1, norm, YAb, YBt, YC8, N, 4);
  k_propA<<<PB, 256, 0, stream>>>(YC8, YBt, offs, csr_srcnode, norm, Qt8, N);
  k_propB<<<PB, 256, 0, stream>>>(Qt8, YAb, b1, offs, csr_srcnode, norm, H1, N);

  // ----- layer 2: A = H1 bf16, K=128 -----
  k_mm3<1><<<MB, 256, 0, stream>>>(H1, nullptr, 0, Wf2, norm, YAb, YBt, YC8, N, 2);
  k_propA<<<PB, 256, 0, stream>>>(YC8, YBt, offs, csr_srcnode, norm, Qt8, N);
  k_propB<<<PB, 256, 0, stream>>>(Qt8, YAb, b2, offs, csr_srcnode, norm, H2, N);

  // readout
  k_colsum<<<256, 128, 0, stream>>>(H2, hg, N);
  k_final<<<1, 128, 0, stream>>>(hg, Wp, bp, (float*)d_out, 1.0f / (float)N);
}

// Round 17
// 808.472 us; speedup vs baseline: 1.1240x; 1.0212x over previous
//
#include <hip/hip_runtime.h>
#include <hip/hip_bf16.h>

// ---------------------------------------------------------------------------
// graphNN round 17 (= R16 + 8-deep ILP in prop gathers):
//  - propA/propB: 8 independent accumulator groups / 8 in-flight gathers
//    (was 4) -> serial latency rounds per node halve
//  - everything else identical to R16 (825us best; absmax 2.93e-3 margin)
// ---------------------------------------------------------------------------

typedef __attribute__((ext_vector_type(8))) short short8;
typedef __attribute__((ext_vector_type(4))) float f32x4;
typedef __attribute__((ext_vector_type(4))) unsigned u32x4;
typedef unsigned short ushort_t;
typedef unsigned char uchar_t;

static __device__ __forceinline__ unsigned short f2bf(float x) {
  union { float f; unsigned u; } v{x};
  unsigned r = v.u + 0x7FFF + ((v.u >> 16) & 1);
  return (unsigned short)(r >> 16);
}
static __device__ __forceinline__ float bf2f(unsigned short h) {
  union { unsigned u; float f; } v{(unsigned)h << 16};
  return v.f;
}
static __device__ __forceinline__ float u2f(unsigned u) {
  union { unsigned u; float f; } v{u};
  return v.f;
}
static __device__ __forceinline__ unsigned cvtpk(float a, float b) {
  unsigned r;
  asm("v_cvt_pk_bf16_f32 %0, %1, %2" : "=v"(r) : "v"(a), "v"(b));
  return r;
}
static __device__ __forceinline__ uchar_t f2fp8(float x) {
  return (uchar_t)(__builtin_amdgcn_cvt_pk_fp8_f32(x, 0.f, 0, false) & 0xff);
}
static __device__ __forceinline__ ushort_t pk2fp8(float a, float b) {
  return (ushort_t)(__builtin_amdgcn_cvt_pk_fp8_f32(a, b, 0, false) & 0xffff);
}

// ---------- fused init: deg histogram (blocks 0..1023) + weight prep --------
__global__ void k_init(const int* __restrict__ dst, int* __restrict__ deg, int E,
                       const float* __restrict__ msg_W, const float* __restrict__ W1,
                       const float* __restrict__ W2, ushort_t* __restrict__ WfT,
                       ushort_t* __restrict__ WfB, ushort_t* __restrict__ Wf1,
                       ushort_t* __restrict__ Wf2) {
  if (blockIdx.x < 1024) {
    int i = blockIdx.x * 256 + threadIdx.x;
    int stride = 1024 * 256;
    for (; i < E; i += stride) atomicAdd(&deg[dst[i]], 1);
    return;
  }
  int id = (blockIdx.x - 1024) * 256 + threadIdx.x;
  const float* W;
  ushort_t* dh;
  int lid;
  if (id < 16384) {  // WfT: KC=2
    W = msg_W; dh = WfT; lid = id;
  } else if (id < 24576) {  // WfB: KC=1
    W = msg_W + 128 * 128; dh = WfB; lid = id - 16384;
  } else if (id < 122880) {  // Wf1: 3 slices, KC=4
    int sub = id - 24576;
    int s = sub >> 15;
    lid = sub & 32767;
    W = W1 + (size_t)s * 256 * 128;
    dh = Wf1 + (size_t)s * 32768;
  } else if (id < 172032) {  // Wf2: 3 slices, KC=2
    int sub = id - 122880;
    int s = sub >> 14;
    lid = sub & 16383;
    W = W2 + (size_t)s * 128 * 128;
    dh = Wf2 + (size_t)s * 16384;
  } else {
    return;
  }
  int j = lid & 7;
  int l = (lid >> 3) & 63;
  int rest = lid >> 9;
  int ks = rest & 1, nt = (rest >> 1) & 7, kc = rest >> 4;
  int k = kc * 64 + ks * 32 + (l >> 4) * 8 + j;
  int col = nt * 16 + (l & 15);
  dh[lid] = f2bf(W[(size_t)k * 128 + col]);
}

// ---------- CSR fill ----------
__global__ void k_csr(const int* __restrict__ src, const int* __restrict__ dst,
                      int* __restrict__ cursor, int* __restrict__ csr_srcnode,
                      int* __restrict__ csr_eid, int* __restrict__ pos2node, int E) {
  int i = blockIdx.x * blockDim.x + threadIdx.x;
  int stride = gridDim.x * blockDim.x;
  for (; i < E; i += stride) {
    int d = dst[i];
    int pos = atomicAdd(&cursor[d], 1);
    csr_srcnode[pos] = src[i];
    csr_eid[pos] = i;
    pos2node[pos] = d;
  }
}

// stage 16 fp32 -> bf16-hi LDS fragment slots
static __device__ __forceinline__ void stage_hi(const float* base, int sq, int sr,
                                                ushort_t* Xh) {
#pragma unroll
  for (int i2 = 0; i2 < 2; ++i2) {
    const int o = sq * 2 + i2;
    f32x4 a4 = *(const f32x4*)(base + sq * 16 + i2 * 8);
    f32x4 b4 = *(const f32x4*)(base + sq * 16 + i2 * 8 + 4);
    u32x4 vh;
    vh[0] = cvtpk(a4[0], a4[1]);
    vh[1] = cvtpk(a4[2], a4[3]);
    vh[2] = cvtpk(b4[0], b4[1]);
    vh[3] = cvtpk(b4[2], b4[3]);
    const int slot = (sr >> 4) * 128 + o * 16 + (sr & 15);
    *(u32x4*)(Xh + (size_t)slot * 8) = vh;
  }
}

// ---------- fused: block 0 = scan(deg->offs,cursor,norm); rest = Z GEMM -----
__global__ __launch_bounds__(256) void k_scan_mmz(
    const int* __restrict__ deg, float* __restrict__ norm, int* __restrict__ offs,
    int* __restrict__ cursor, int N, const float* __restrict__ A0,
    const ushort_t* __restrict__ Wf, const float* __restrict__ bias,
    uchar_t* __restrict__ outZ8, int KC) {
  __shared__ __align__(16) char lds[24576];
  if (blockIdx.x == 0) {
    int* part = (int*)lds;
    const int t = threadIdx.x;
    const int C = (N + 255) >> 8;
    const int b = t * C, e = min(b + C, N);
    int s = 0;
    for (int i = b; i < e; ++i) s += deg[i];
    part[t] = s;
    __syncthreads();
    for (int ofs = 1; ofs < 256; ofs <<= 1) {
      int v = (t >= ofs) ? part[t - ofs] : 0;
      __syncthreads();
      part[t] += v;
      __syncthreads();
    }
    int base = (t == 0) ? 0 : part[t - 1];
    for (int i = b; i < e; ++i) {
      offs[i] = base;
      cursor[i] = base;
      int d = deg[i];
      base += d;
      norm[i] = rsqrtf((float)max(d, 1));
    }
    if (t == 0) offs[N] = part[255];
    return;
  }
  ushort_t* Xh = (ushort_t*)lds;            // 8KB
  ushort_t* Whi = (ushort_t*)(lds + 8192);  // 16KB
  const int t = threadIdx.x;
  const int m0 = (blockIdx.x - 1) * 64;
  const int l = t & 63, mt = t >> 6;
  const int sr = t & 63, sq = t >> 6;
  const int row = min(m0 + sr, N - 1);

  f32x4 acc[8];
#pragma unroll
  for (int nt = 0; nt < 8; ++nt) acc[nt] = (f32x4){0.f, 0.f, 0.f, 0.f};

  for (int kc = 0; kc < KC; ++kc) {
    __syncthreads();
    {
      const ulong2* gh = (const ulong2*)(Wf + (size_t)kc * 8192);
#pragma unroll
      for (int i = 0; i < 4; ++i) ((ulong2*)Whi)[i * 256 + t] = gh[i * 256 + t];
    }
    stage_hi(A0 + (size_t)row * 128 + kc * 64, sq, sr, Xh);
    __syncthreads();
    const short8* Xh8 = (const short8*)Xh;
    const short8* Wh8 = (const short8*)Whi;
#pragma unroll
    for (int ks = 0; ks < 2; ++ks) {
      short8 ah = Xh8[mt * 128 + ks * 64 + l];
#pragma unroll
      for (int nt = 0; nt < 8; ++nt)
        acc[nt] = __builtin_amdgcn_mfma_f32_16x16x32_bf16(
            ah, Wh8[(nt * 2 + ks) * 64 + l], acc[nt], 0, 0, 0);
    }
  }
  const int l15 = l & 15, lh = l >> 4;
#pragma unroll
  for (int nt = 0; nt < 8; ++nt) {
    const int col = nt * 16 + l15;
#pragma unroll
    for (int rg = 0; rg < 4; ++rg) {
      const int r = m0 + mt * 16 + lh * 4 + rg;
      if (r < N) outZ8[(size_t)r * 128 + col] = f2fp8(acc[nt][rg] + bias[col]);
    }
  }
}

// ---------- fused 3-slice GEMM: YA bf16, YBt bf16, YC8 fp8 ------------------
template <int BF16A>
__global__ __launch_bounds__(256) void k_mm3(
    const void* __restrict__ A0v, const float* __restrict__ A1, int split64,
    const ushort_t* __restrict__ Wf, const float* __restrict__ rowscale,
    ushort_t* __restrict__ outYA, ushort_t* __restrict__ outYB,
    uchar_t* __restrict__ outYC8, int M, int KC) {
  __shared__ __align__(16) char lds[24576];
  ushort_t* Xh = (ushort_t*)lds;            // 8KB
  ushort_t* Whi = (ushort_t*)(lds + 8192);  // 16KB

  const int t = threadIdx.x;
  const int m0 = blockIdx.x * 64;
  const int l = t & 63, mt = t >> 6;
  const int sr = t & 63, sq = t >> 6;
  const int row = min(m0 + sr, M - 1);

  f32x4 acc[3][8];
#pragma unroll
  for (int s = 0; s < 3; ++s)
#pragma unroll
    for (int nt = 0; nt < 8; ++nt) acc[s][nt] = (f32x4){0.f, 0.f, 0.f, 0.f};

  for (int kc = 0; kc < KC; ++kc) {
    __syncthreads();
    if constexpr (BF16A) {
      const ushort_t* base = (const ushort_t*)A0v + (size_t)row * 128 + kc * 64;
#pragma unroll
      for (int i2 = 0; i2 < 2; ++i2) {
        const int o = sq * 2 + i2;
        short8 v = *(const short8*)(base + sq * 16 + i2 * 8);
        const int slot = (sr >> 4) * 128 + o * 16 + (sr & 15);
        *(short8*)(Xh + (size_t)slot * 8) = v;
      }
    } else {
      const float* A0 = (const float*)A0v;
      const float* base = (kc < split64) ? (A0 + (size_t)row * 128 + kc * 64)
                                         : (A1 + (size_t)row * 128 + (kc - split64) * 64);
      stage_hi(base, sq, sr, Xh);
    }
#pragma unroll
    for (int s = 0; s < 3; ++s) {
      if (s) __syncthreads();
      {
        const ulong2* gh = (const ulong2*)(Wf + ((size_t)s * KC + kc) * 8192);
#pragma unroll
        for (int i = 0; i < 4; ++i) ((ulong2*)Whi)[i * 256 + t] = gh[i * 256 + t];
      }
      __syncthreads();
      const short8* Xh8 = (const short8*)Xh;
      const short8* Wh8 = (const short8*)Whi;
#pragma unroll
      for (int ks = 0; ks < 2; ++ks) {
        short8 ah = Xh8[mt * 128 + ks * 64 + l];
#pragma unroll
        for (int nt = 0; nt < 8; ++nt)
          acc[s][nt] = __builtin_amdgcn_mfma_f32_16x16x32_bf16(
              ah, Wh8[(nt * 2 + ks) * 64 + l], acc[s][nt], 0, 0, 0);
      }
    }
  }
  const int l15 = l & 15, lh = l >> 4;
#pragma unroll
  for (int rg = 0; rg < 4; ++rg) {
    const int r = m0 + mt * 16 + lh * 4 + rg;
    if (r < M) {
      const float rs = rowscale[r];
#pragma unroll
      for (int nt = 0; nt < 8; ++nt) {
        const int col = nt * 16 + l15;
        outYA[(size_t)r * 128 + col] = f2bf(acc[0][nt][rg]);
        outYB[(size_t)r * 128 + col] = f2bf(acc[1][nt][rg] * rs);
        outYC8[(size_t)r * 128 + col] = f2fp8(acc[2][nt][rg] * rs);
      }
    }
  }
}

// ---------- edge GEMM: 64 edges/block, 512 threads (8 waves, 4 blk/CU) ------
__global__ __launch_bounds__(512, 8) void k_edge(
    const float* __restrict__ ef, const int* __restrict__ csr_srcnode,
    const int* __restrict__ csr_eid, const int* __restrict__ pos2node,
    const ushort_t* __restrict__ WfB, const uchar_t* __restrict__ Z8,
    float* __restrict__ h_neigh) {
  __shared__ __align__(16) char lds[33024];
  ushort_t* Whi = (ushort_t*)lds;            // [0,16K)
  ushort_t* Xh = (ushort_t*)(lds + 16384);   // [16K,24K)
  ushort_t* Cs = (ushort_t*)(lds + 16384);   // overlay [16K,32K)
  int* sN = (int*)(lds + 32768);             // [32K,+256)

  const int t = threadIdx.x;
  const int b0 = blockIdx.x * 64;
  const int l = t & 63, w = t >> 6;          // 8 waves
  const int mt = w >> 1, nh = w & 1;         // M-tile 0..3, N-half
  const int col = t & 127, g = t >> 7;       // 4 walk groups x 16 rows
  const int rbase = b0 + g * 16;

  // ---- Z prefetch (fp8 bytes) ----
  uchar_t z8[16];
#pragma unroll
  for (int i = 0; i < 16; ++i)
    z8[i] = Z8[(size_t)csr_srcnode[rbase + i] * 128 + col];
  // ---- stage W (two 16B per thread, contiguous) ----
  ((ulong2*)Whi)[t] = ((const ulong2*)WfB)[t];
  ((ulong2*)Whi)[t + 512] = ((const ulong2*)WfB)[t + 512];
  // ---- stage ef rows: 8 threads/row (coalesced 256B/row) ----
  {
    const int row = t >> 3, part = t & 7;
    const int eid = csr_eid[b0 + row];
    const float* rowp = ef + (size_t)eid * 64 + part * 8;
    f32x4 a4 = __builtin_nontemporal_load((const f32x4*)rowp);
    f32x4 b4 = __builtin_nontemporal_load((const f32x4*)(rowp + 4));
    u32x4 vh;
    vh[0] = cvtpk(a4[0], a4[1]);
    vh[1] = cvtpk(a4[2], a4[3]);
    vh[2] = cvtpk(b4[0], b4[1]);
    vh[3] = cvtpk(b4[2], b4[3]);
    const int slot = (row >> 4) * 128 + part * 16 + (row & 15);
    *(u32x4*)(Xh + (size_t)slot * 8) = vh;
  }
  __syncthreads();

  f32x4 acc[4];
#pragma unroll
  for (int nt = 0; nt < 4; ++nt) acc[nt] = (f32x4){0.f, 0.f, 0.f, 0.f};
  {
    const short8* Xh8 = (const short8*)Xh;
    const short8* Wh8 = (const short8*)Whi;
#pragma unroll
    for (int ks = 0; ks < 2; ++ks) {
      short8 ah = Xh8[mt * 128 + ks * 64 + l];
#pragma unroll
      for (int nt = 0; nt < 4; ++nt) {
        const int ntg = nh * 4 + nt;
        acc[nt] = __builtin_amdgcn_mfma_f32_16x16x32_bf16(
            ah, Wh8[(ntg * 2 + ks) * 64 + l], acc[nt], 0, 0, 0);
      }
    }
  }
  __syncthreads();
  // ---- preload node ids + C tile to LDS (bank-correct swizzle) ----
  if (t < 64) sN[t] = pos2node[b0 + t];
  const int l15 = l & 15, lh = l >> 4;
#pragma unroll
  for (int nt = 0; nt < 4; ++nt) {
#pragma unroll
    for (int rg = 0; rg < 4; ++rg) {
      const int row = mt * 16 + lh * 4 + rg;
      const int c = nh * 64 + nt * 16 + l15;
      Cs[row * 128 + (c ^ (((row >> 2) & 3) << 4))] = f2bf(acc[nt][rg]);
    }
  }
  __syncthreads();
  // ---- 4-way parallel segment walk (16 rows each) ----
  {
    int node = sN[g * 16];
    float ssum = 0.f;
#pragma unroll
    for (int r = 0; r < 16; ++r) {
      const int rr = g * 16 + r;
      float cz = bf2f(Cs[rr * 128 + (col ^ (((rr >> 2) & 3) << 4))]);
      float zf = __builtin_amdgcn_cvt_f32_fp8((int)z8[r], 0);
      float v = fmaxf(cz + zf, 0.f);
      if (r == 0) {
        ssum = v;
      } else {
        int n2 = sN[rr];
        if (n2 == node) {
          ssum += v;
        } else {
          unsafeAtomicAdd(&h_neigh[(size_t)node * 128 + col], ssum);
          node = n2;
          ssum = v;
        }
      }
    }
    unsafeAtomicAdd(&h_neigh[(size_t)node * 128 + col], ssum);
  }
}

// ---------- propA: Qt8 = fp8(YBt + n^2 * sum YC8[src])  (8-acc ILP) ---------
__global__ __launch_bounds__(256) void k_propA(
    const uchar_t* __restrict__ YC8, const ushort_t* __restrict__ YBt,
    const int* __restrict__ offs, const int* __restrict__ csr_src,
    const float* __restrict__ norm, uchar_t* __restrict__ Qt8, int N) {
  const int v = blockIdx.x * 4 + (threadIdx.x >> 6);
  const int lane = threadIdx.x & 63;
  if (v >= N) return;
  const int b = offs[v], e = offs[v + 1];
  const ushort_t* yc = (const ushort_t*)YC8;
  float ax[8], ay[8];
#pragma unroll
  for (int j = 0; j < 8; ++j) { ax[j] = 0.f; ay[j] = 0.f; }
  int i = b;
  const int e8 = b + ((e - b) & ~7);
  for (; i < e8; i += 8) {
    int xs[8];
#pragma unroll
    for (int j = 0; j < 8; ++j) xs[j] = yc[(size_t)csr_src[i + j] * 64 + lane];
#pragma unroll
    for (int j = 0; j < 8; ++j) {
      auto d = __builtin_amdgcn_cvt_pk_f32_fp8(xs[j], false);
      ax[j] += d[0];
      ay[j] += d[1];
    }
  }
  for (; i < e; ++i) {
    const int x = yc[(size_t)csr_src[i] * 64 + lane];
    auto d = __builtin_amdgcn_cvt_pk_f32_fp8(x, false);
    ax[0] += d[0];
    ay[0] += d[1];
  }
  const float axs = ((ax[0] + ax[1]) + (ax[2] + ax[3])) + ((ax[4] + ax[5]) + (ax[6] + ax[7]));
  const float ays = ((ay[0] + ay[1]) + (ay[2] + ay[3])) + ((ay[4] + ay[5]) + (ay[6] + ay[7]));
  const float n = norm[v];
  const float n2 = n * n;
  const unsigned yb = ((const unsigned*)YBt)[(size_t)v * 64 + lane];
  ((ushort_t*)Qt8)[(size_t)v * 64 + lane] =
      pk2fp8(u2f(yb << 16) + n2 * axs, u2f(yb & 0xffff0000u) + n2 * ays);
}

// ---------- propB: H = bf16(relu(YA + n * sum Qt8[src] + b))  (8-acc ILP) ---
__global__ __launch_bounds__(256) void k_propB(
    const uchar_t* __restrict__ Qt8, const ushort_t* __restrict__ YAb,
    const float* __restrict__ bias, const int* __restrict__ offs,
    const int* __restrict__ csr_src, const float* __restrict__ norm,
    ushort_t* __restrict__ H, int N) {
  const int v = blockIdx.x * 4 + (threadIdx.x >> 6);
  const int lane = threadIdx.x & 63;
  if (v >= N) return;
  const int b = offs[v], e = offs[v + 1];
  const ushort_t* qp = (const ushort_t*)Qt8;
  float ax[8], ay[8];
#pragma unroll
  for (int j = 0; j < 8; ++j) { ax[j] = 0.f; ay[j] = 0.f; }
  int i = b;
  const int e8 = b + ((e - b) & ~7);
  for (; i < e8; i += 8) {
    int xs[8];
#pragma unroll
    for (int j = 0; j < 8; ++j) xs[j] = qp[(size_t)csr_src[i + j] * 64 + lane];
#pragma unroll
    for (int j = 0; j < 8; ++j) {
      auto d = __builtin_amdgcn_cvt_pk_f32_fp8(xs[j], false);
      ax[j] += d[0];
      ay[j] += d[1];
    }
  }
  for (; i < e; ++i) {
    const int x = qp[(size_t)csr_src[i] * 64 + lane];
    auto d = __builtin_amdgcn_cvt_pk_f32_fp8(x, false);
    ax[0] += d[0];
    ay[0] += d[1];
  }
  const float axs = ((ax[0] + ax[1]) + (ax[2] + ax[3])) + ((ax[4] + ax[5]) + (ax[6] + ax[7]));
  const float ays = ((ay[0] + ay[1]) + (ay[2] + ay[3])) + ((ay[4] + ay[5]) + (ay[6] + ay[7]));
  const float n = norm[v];
  const unsigned ya = ((const unsigned*)YAb)[(size_t)v * 64 + lane];
  const float2 bb = ((const float2*)bias)[lane];
  const float hx = fmaxf(u2f(ya << 16) + n * axs + bb.x, 0.f);
  const float hy = fmaxf(u2f(ya & 0xffff0000u) + n * ays + bb.y, 0.f);
  ((unsigned*)H)[(size_t)v * 64 + lane] = cvtpk(hx, hy);
}

// ---------- column sums of bf16 h -> hg[128] ----------
__global__ void k_colsum(const ushort_t* __restrict__ h, float* __restrict__ hg, int N) {
  const int t = threadIdx.x;  // 128
  const int per = (N + gridDim.x - 1) / gridDim.x;
  const int n0 = blockIdx.x * per, n1 = min(n0 + per, N);
  float s = 0.f;
  for (int n = n0; n < n1; ++n) s += bf2f(h[(size_t)n * 128 + t]);
  unsafeAtomicAdd(&hg[t], s);
}

// ---------- final ----------
__global__ void k_final(const float* __restrict__ hg, const float* __restrict__ Wp,
                        const float* __restrict__ bp, float* __restrict__ out,
                        float invN) {
  __shared__ float red[128];
  const int t = threadIdx.x;
  red[t] = hg[t] * invN * Wp[t];
  __syncthreads();
  for (int s = 64; s > 0; s >>= 1) {
    if (t < s) red[t] += red[t + s];
    __syncthreads();
  }
  if (t == 0) out[0] = red[0] + bp[0];
}

extern "C" void kernel_launch(void* const* d_in, const int* in_sizes, int n_in,
                              void* d_out, int out_size, void* d_ws, size_t ws_size,
                              hipStream_t stream) {
  const float* node_fea = (const float*)d_in[0];
  const float* edge_fea = (const float*)d_in[1];
  const int* src = (const int*)d_in[2];
  const int* dst = (const int*)d_in[3];
  const float* msg_W = (const float*)d_in[4];
  const float* msg_b = (const float*)d_in[5];
  const float* W1 = (const float*)d_in[6];
  const float* b1 = (const float*)d_in[7];
  const float* W2 = (const float*)d_in[8];
  const float* b2 = (const float*)d_in[9];
  const float* Wp = (const float*)d_in[10];
  const float* bp = (const float*)d_in[11];

  const int N = in_sizes[0] / 128;  // 50000
  const int E = in_sizes[2];        // 1600000

  char* p = (char*)d_ws;
  auto alloc = [&](size_t bytes) {
    char* r = p;
    p += (bytes + 255) & ~(size_t)255;
    return r;
  };
  int* deg = (int*)alloc((size_t)N * 4);
  float* norm = (float*)alloc((size_t)N * 4);
  int* offs = (int*)alloc((size_t)(N + 1) * 4);
  int* cursor = (int*)alloc((size_t)N * 4);
  int* csr_srcnode = (int*)alloc((size_t)E * 4);
  int* csr_eid = (int*)alloc((size_t)E * 4);
  int* pos2node = (int*)alloc((size_t)E * 4);
  ushort_t* WfT = (ushort_t*)alloc(2 * 8192 * 2);
  ushort_t* WfB = (ushort_t*)alloc(1 * 8192 * 2);
  ushort_t* Wf1 = (ushort_t*)alloc(3 * 4 * 8192 * 2);
  ushort_t* Wf2 = (ushort_t*)alloc(3 * 2 * 8192 * 2);
  uchar_t* Z8 = (uchar_t*)alloc((size_t)N * 128);         // fp8 Z
  ushort_t* YAb = (ushort_t*)alloc((size_t)N * 128 * 2);  // bf16 YA
  float* hn = (float*)alloc((size_t)N * 128 * 4);
  ushort_t* YBt = (ushort_t*)alloc((size_t)N * 128 * 2);  // bf16 (streamed)
  uchar_t* YC8 = (uchar_t*)alloc((size_t)N * 128);        // fp8 (gathered)
  uchar_t* Qt8 = (uchar_t*)alloc((size_t)N * 128);        // fp8 (gathered)
  ushort_t* H1 = (ushort_t*)alloc((size_t)N * 128 * 2);
  ushort_t* H2 = (ushort_t*)alloc((size_t)N * 128 * 2);
  float* hg = (float*)alloc(128 * 4);

  (void)hipMemsetAsync(deg, 0, (size_t)N * 4, stream);
  (void)hipMemsetAsync(hn, 0, (size_t)N * 128 * 4, stream);
  (void)hipMemsetAsync(hg, 0, 128 * 4, stream);

  // fused: deg histogram + all weight prep
  k_init<<<1696, 256, 0, stream>>>(dst, deg, E, msg_W, W1, W2, WfT, WfB, Wf1, Wf2);

  const int MB = (N + 63) / 64;  // 782
  const int PB = (N + 3) / 4;

  // fused: scan (block 0) + Z = node_fea @ W_top + b (blocks 1..MB)
  k_scan_mmz<<<MB + 1, 256, 0, stream>>>(deg, norm, offs, cursor, N, node_fea,
                                         WfT, msg_b, Z8, 2);
  // CSR fill
  k_csr<<<2048, 256, 0, stream>>>(src, dst, cursor, csr_srcnode, csr_eid, pos2node, E);
  // edge messages -> hn (64 edges/block, 512 threads, 4 blocks/CU)
  k_edge<<<E / 64, 512, 0, stream>>>(edge_fea, csr_srcnode, csr_eid, pos2node,
                                     WfB, Z8, hn);

  // ----- layer 1: A = [node_fea | hn] fp32, K=256 -----
  k_mm3<0><<<MB, 256, 0, stream>>>(node_fea, hn, 2, Wf1, norm, YAb, YBt, YC8, N, 4);
  k_propA<<<PB, 256, 0, stream>>>(YC8, YBt, offs, csr_srcnode, norm, Qt8, N);
  k_propB<<<PB, 256, 0, stream>>>(Qt8, YAb, b1, offs, csr_srcnode, norm, H1, N);

  // ----- layer 2: A = H1 bf16, K=128 -----
  k_mm3<1><<<MB, 256, 0, stream>>>(H1, nullptr, 0, Wf2, norm, YAb, YBt, YC8, N, 2);
  k_propA<<<PB, 256, 0, stream>>>(YC8, YBt, offs, csr_srcnode, norm, Qt8, N);
  k_propB<<<PB, 256, 0, stream>>>(Qt8, YAb, b2, offs, csr_srcnode, norm, H2, N);

  // readout
  k_colsum<<<256, 128, 0, stream>>>(H2, hg, N);
  k_final<<<1, 128, 0, stream>>>(hg, Wp, bp, (float*)d_out, 1.0f / (float)N);
}